// Round 1
// baseline (417.164 us; speedup 1.0000x reference)
//
#include <hip/hip_runtime.h>
#include <hip/hip_bf16.h>

#define T_SEQ 2048
#define DMODEL 2048
#define NB 2
#define NH 16
#define HD 128

typedef __attribute__((ext_vector_type(8))) short short8;
typedef __attribute__((ext_vector_type(4))) float f32x4;
typedef unsigned short ushort_t;

__device__ inline ushort_t f2bf(float f) {
  union { float f; unsigned u; } v; v.f = f;
  unsigned r = v.u + 0x7fffu + ((v.u >> 16) & 1u);
  return (ushort_t)(r >> 16);
}
__device__ inline float bf2f(ushort_t u) {
  union { unsigned u; float f; } v; v.u = ((unsigned)u) << 16;
  return v.f;
}

__device__ inline void gload16(const void* g, void* l) {
  __builtin_amdgcn_global_load_lds(
      (const __attribute__((address_space(1))) unsigned*)g,
      (__attribute__((address_space(3))) unsigned*)l, 16, 0, 0);
}

// ---------------- fp32 -> bf16 convert, 8 elems/thread ----------------
__global__ void cvt_f32_bf16(const float* __restrict__ src, ushort_t* __restrict__ dst, int n8) {
  int i = blockIdx.x * blockDim.x + threadIdx.x;
  if (i >= n8) return;
  const float4* s = (const float4*)src + (size_t)i * 2;
  float4 a = s[0], b = s[1];
  short8 o;
  o[0] = (short)f2bf(a.x); o[1] = (short)f2bf(a.y);
  o[2] = (short)f2bf(a.z); o[3] = (short)f2bf(a.w);
  o[4] = (short)f2bf(b.x); o[5] = (short)f2bf(b.y);
  o[6] = (short)f2bf(b.z); o[7] = (short)f2bf(b.w);
  *((short8*)dst + i) = o;
}

// ---------------- cos/sin table: trig[t*128 + i*2] = cos, +1 = sin ----
__global__ void trig_init(float* __restrict__ trig) {
  int idx = blockIdx.x * blockDim.x + threadIdx.x;  // T*64
  if (idx >= T_SEQ * 64) return;
  int i = idx & 63, t = idx >> 6;
  // inv_freq = 10000^(-i/64)
  float inv = __expf(-(float)i * (9.210340371976184f / 64.0f));
  float f = (float)t * inv;
  trig[idx * 2]     = cosf(f);
  trig[idx * 2 + 1] = sinf(f);
}

// ---------------- RoPE in-place on q,k ([B][H][T][128] bf16) ----------
__global__ void rope_kernel(ushort_t* __restrict__ q, ushort_t* __restrict__ k,
                            const float* __restrict__ trig) {
  int idx = blockIdx.x * blockDim.x + threadIdx.x;  // NB*T*NH*16
  int i8 = idx & 15;
  int h  = (idx >> 4) & 15;
  int t  = (idx >> 8) & (T_SEQ - 1);
  int b  = idx >> 19;
  size_t base = ((size_t)((b * NH + h) * T_SEQ + t)) * HD + i8 * 8;
  const float4* tr = (const float4*)(trig + t * 128 + i8 * 8);
  float4 t0 = tr[0], t1 = tr[1];
  float c[4] = { t0.x, t0.z, t1.x, t1.z };
  float s[4] = { t0.y, t0.w, t1.y, t1.w };
  short8 vq = *(short8*)(q + base);
  short8 vk = *(short8*)(k + base);
  short8 oq, ok;
#pragma unroll
  for (int j = 0; j < 4; ++j) {
    float x1 = bf2f((ushort_t)vq[2*j]), x2 = bf2f((ushort_t)vq[2*j+1]);
    oq[2*j]   = (short)f2bf(x1 * c[j] - x2 * s[j]);
    oq[2*j+1] = (short)f2bf(x1 * s[j] + x2 * c[j]);
    x1 = bf2f((ushort_t)vk[2*j]); x2 = bf2f((ushort_t)vk[2*j+1]);
    ok[2*j]   = (short)f2bf(x1 * c[j] - x2 * s[j]);
    ok[2*j+1] = (short)f2bf(x1 * s[j] + x2 * c[j]);
  }
  *(short8*)(q + base) = oq;
  *(short8*)(k + base) = ok;
}

// ---------------- V transpose: [B][H][T][128] -> [B][H][128][T] -------
__global__ __launch_bounds__(256)
void v_transpose(const ushort_t* __restrict__ v, ushort_t* __restrict__ vt) {
  __shared__ __align__(16) ushort_t L[64][136];
  int bh = blockIdx.y;
  int t0 = blockIdx.x * 64;
  int tid = threadIdx.x;
  int row = tid >> 2, c0 = (tid & 3) * 32;
  const ushort_t* src = v + ((size_t)bh * T_SEQ + t0 + row) * HD + c0;
#pragma unroll
  for (int j = 0; j < 4; ++j)
    *(short8*)&L[row][c0 + j * 8] = *(const short8*)(src + j * 8);
  __syncthreads();
  int d = tid >> 1, tc = (tid & 1) * 32;
  union { ushort_t u[32]; short8 v8[4]; } buf;
#pragma unroll
  for (int j = 0; j < 32; ++j) buf.u[j] = L[tc + j][d];
  ushort_t* dst = vt + ((size_t)bh * HD + d) * T_SEQ + t0 + tc;
#pragma unroll
  for (int j = 0; j < 4; ++j) *(short8*)(dst + j * 8) = buf.v8[j];
}

// ---------------- GEMM C = A * Bt^T (bf16 in, fp32 acc) ---------------
// A[M][K], Bt[N][K] row-major bf16. 128x128 tile, BK=32, 256 thr (2x2 waves).
// EPI=0: C fp32 [M][N].  EPI=1: scatter bf16 into q/k/v [B][H][T][128].
template <int EPI>
__global__ __launch_bounds__(256)
void gemm_bt(const ushort_t* __restrict__ A, const ushort_t* __restrict__ Bt,
             float* __restrict__ C, ushort_t* __restrict__ q_t,
             ushort_t* __restrict__ k_t, ushort_t* __restrict__ v_t,
             int M, int N, int K) {
  __shared__ __align__(16) ushort_t As[128 * 32];
  __shared__ __align__(16) ushort_t Bs[128 * 32];
  int tid = threadIdx.x, lane = tid & 63, w = tid >> 6;
  int wm = w >> 1, wn = w & 1;
  int li = lane & 15, lg = lane >> 4;
  int tile_n = blockIdx.x * 128, tile_m = blockIdx.y * 128;
  f32x4 acc[4][4] = {};
  int arow = lane >> 2, acol = (lane & 3) * 8;
  const ushort_t* Ag = A + (size_t)tile_m * K;
  const ushort_t* Bg = Bt + (size_t)tile_n * K;
  for (int k0 = 0; k0 < K; k0 += 32) {
#pragma unroll
    for (int i = 0; i < 2; ++i) {
      int blk = w * 2 + i;
      gload16(Ag + (size_t)(blk * 16 + arow) * K + k0 + acol, &As[blk * 512]);
      gload16(Bg + (size_t)(blk * 16 + arow) * K + k0 + acol, &Bs[blk * 512]);
    }
    __syncthreads();
    short8 af[4], bf[4];
#pragma unroll
    for (int mi = 0; mi < 4; ++mi)
      af[mi] = *(const short8*)&As[(wm * 64 + mi * 16 + li) * 32 + lg * 8];
#pragma unroll
    for (int ni = 0; ni < 4; ++ni)
      bf[ni] = *(const short8*)&Bs[(wn * 64 + ni * 16 + li) * 32 + lg * 8];
#pragma unroll
    for (int mi = 0; mi < 4; ++mi)
#pragma unroll
      for (int ni = 0; ni < 4; ++ni)
        acc[mi][ni] = __builtin_amdgcn_mfma_f32_16x16x32_bf16(af[mi], bf[ni], acc[mi][ni], 0, 0, 0);
    __syncthreads();
  }
#pragma unroll
  for (int mi = 0; mi < 4; ++mi) {
    int row = tile_m + wm * 64 + mi * 16 + lg * 4;
#pragma unroll
    for (int ni = 0; ni < 4; ++ni) {
      int col = tile_n + wn * 64 + ni * 16 + li;
#pragma unroll
      for (int r = 0; r < 4; ++r) {
        float val = acc[mi][ni][r];
        if (EPI == 0) {
          C[(size_t)(row + r) * N + col] = val;
        } else {
          int m = row + r;
          int b = m >> 11, t = m & 2047;
          int sec = col >> 11, nn = col & 2047;
          int h = nn >> 7, d = nn & 127;
          ushort_t* dst = (sec == 0) ? q_t : ((sec == 1) ? k_t : v_t);
          dst[((size_t)((b * NH + h) * T_SEQ + t)) * HD + d] = f2bf(val);
        }
      }
    }
  }
}

// ---------------- Flash attention (causal) ----------------------------
// Q,K: [B*H][T][128] bf16 (roped). Vt: [B*H][128][T] bf16. Y: [B*T][2048] bf16.
// grid (T/64, B*H), 256 threads. Wave w owns q-rows [q0+16w, q0+16w+16).
__global__ __launch_bounds__(256)
void flash_attn(const ushort_t* __restrict__ Q, const ushort_t* __restrict__ Kg,
                const ushort_t* __restrict__ Vt, ushort_t* __restrict__ Y) {
  __shared__ __align__(16) ushort_t Ks[64 * 128];   // [kv][128], XOR-swizzled
  __shared__ __align__(16) ushort_t Vs[128 * 64];   // [d][kv],  XOR-swizzled
  __shared__ __align__(16) ushort_t Ps[4][16 * 72]; // per-wave P, padded
  int tid = threadIdx.x, lane = tid & 63, w = tid >> 6;
  int li = lane & 15, lg = lane >> 4;
  int qt = blockIdx.x, bh = blockIdx.y;
  int b = bh >> 4, h = bh & 15;
  int q0 = qt * 64;
  const ushort_t* Qp = Q + (size_t)bh * T_SEQ * HD;
  const ushort_t* Kp = Kg + (size_t)bh * T_SEQ * HD;
  const ushort_t* Vp = Vt + (size_t)bh * HD * T_SEQ;
  short8 qf[4];
  {
    int qrow = q0 + w * 16 + li;
#pragma unroll
    for (int ks = 0; ks < 4; ++ks)
      qf[ks] = *(const short8*)(Qp + (size_t)qrow * HD + ks * 32 + lg * 8);
  }
  f32x4 o[8] = {};
  float m_r[4], l_r[4];
#pragma unroll
  for (int r = 0; r < 4; ++r) { m_r[r] = -3e38f; l_r[r] = 0.f; }
  const float scale = 0.08838834764831845f;  // 1/sqrt(128)
  for (int kt = 0; kt <= qt; ++kt) {
    int kv0 = kt * 64;
#pragma unroll
    for (int i = 0; i < 4; ++i) {
      int blk = w * 4 + i;
      {  // K tile: 4 rows x 256B per inst; pre-swizzled source
        int row = blk * 4 + lg;
        int kb = (li * 16) ^ ((row & 7) << 4);
        gload16(Kp + (size_t)(kv0 + row) * HD + (kb >> 1), &Ks[blk * 512]);
      }
      {  // Vt tile: 8 rows x 128B per inst
        int d = blk * 8 + (lane >> 3);
        int kb = ((lane & 7) * 16) ^ ((d & 7) << 4);
        gload16(Vp + (size_t)d * T_SEQ + kv0 + (kb >> 1), &Vs[blk * 512]);
      }
    }
    __syncthreads();
    // S = Q K^T * scale
    f32x4 s[4];
#pragma unroll
    for (int nt = 0; nt < 4; ++nt) {
      f32x4 a = {};
      int row = nt * 16 + li;
#pragma unroll
      for (int ks = 0; ks < 4; ++ks) {
        int kb = (ks * 64 + lg * 16) ^ ((row & 7) << 4);
        short8 kf = *(const short8*)&Ks[row * 128 + (kb >> 1)];
        a = __builtin_amdgcn_mfma_f32_16x16x32_bf16(qf[ks], kf, a, 0, 0, 0);
      }
#pragma unroll
      for (int r = 0; r < 4; ++r) s[nt][r] = a[r] * scale;
    }
    if (kt == qt) {
#pragma unroll
      for (int nt = 0; nt < 4; ++nt)
#pragma unroll
        for (int r = 0; r < 4; ++r)
          if (nt * 16 + li > w * 16 + lg * 4 + r) s[nt][r] = -3e30f;
    }
    // row max (16-lane butterfly)
    float mx[4];
#pragma unroll
    for (int r = 0; r < 4; ++r)
      mx[r] = fmaxf(fmaxf(s[0][r], s[1][r]), fmaxf(s[2][r], s[3][r]));
#pragma unroll
    for (int msk = 1; msk <= 8; msk <<= 1)
#pragma unroll
      for (int r = 0; r < 4; ++r)
        mx[r] = fmaxf(mx[r], __shfl_xor(mx[r], msk));
    float alpha[4], mn[4];
#pragma unroll
    for (int r = 0; r < 4; ++r) {
      mn[r] = fmaxf(m_r[r], mx[r]);
      alpha[r] = __expf(m_r[r] - mn[r]);
      m_r[r] = mn[r];
    }
    float p[4][4], rs[4];
#pragma unroll
    for (int r = 0; r < 4; ++r) rs[r] = 0.f;
#pragma unroll
    for (int nt = 0; nt < 4; ++nt)
#pragma unroll
      for (int r = 0; r < 4; ++r) {
        p[nt][r] = __expf(s[nt][r] - mn[r]);
        rs[r] += p[nt][r];
      }
#pragma unroll
    for (int msk = 1; msk <= 8; msk <<= 1)
#pragma unroll
      for (int r = 0; r < 4; ++r)
        rs[r] += __shfl_xor(rs[r], msk);
#pragma unroll
    for (int r = 0; r < 4; ++r) l_r[r] = l_r[r] * alpha[r] + rs[r];
#pragma unroll
    for (int ot = 0; ot < 8; ++ot)
#pragma unroll
      for (int r = 0; r < 4; ++r) o[ot][r] *= alpha[r];
    // P -> per-wave LDS (layout convert C-frag -> A-frag)
#pragma unroll
    for (int nt = 0; nt < 4; ++nt)
#pragma unroll
      for (int r = 0; r < 4; ++r)
        Ps[w][(lg * 4 + r) * 72 + nt * 16 + li] = f2bf(p[nt][r]);
    asm volatile("s_waitcnt lgkmcnt(0)" ::: "memory");
    short8 pf[2];
#pragma unroll
    for (int ks = 0; ks < 2; ++ks)
      pf[ks] = *(const short8*)&Ps[w][li * 72 + ks * 32 + lg * 8];
#pragma unroll
    for (int ot = 0; ot < 8; ++ot) {
      int vrow = ot * 16 + li;
#pragma unroll
      for (int ks = 0; ks < 2; ++ks) {
        int kb = (ks * 64 + lg * 16) ^ ((vrow & 7) << 4);
        short8 vf = *(const short8*)&Vs[vrow * 64 + (kb >> 1)];
        o[ot] = __builtin_amdgcn_mfma_f32_16x16x32_bf16(pf[ks], vf, o[ot], 0, 0, 0);
      }
    }
    __syncthreads();
  }
  float inv_l[4];
#pragma unroll
  for (int r = 0; r < 4; ++r) inv_l[r] = 1.f / l_r[r];
#pragma unroll
  for (int ot = 0; ot < 8; ++ot) {
    int col = h * HD + ot * 16 + li;
#pragma unroll
    for (int r = 0; r < 4; ++r) {
      int t = q0 + w * 16 + lg * 4 + r;
      Y[((size_t)(b * T_SEQ + t)) * DMODEL + col] = f2bf(o[ot][r] * inv_l[r]);
    }
  }
}

extern "C" void kernel_launch(void* const* d_in, const int* in_sizes, int n_in,
                              void* d_out, int out_size, void* d_ws, size_t ws_size,
                              hipStream_t stream) {
  const float* x      = (const float*)d_in[0];
  const float* w_attn = (const float*)d_in[1];
  const float* w_proj = (const float*)d_in[2];
  float* out = (float*)d_out;

  char* ws = (char*)d_ws;
  size_t off = 0;
  auto alloc = [&](size_t bytes) -> void* {
    void* p = ws + off;
    off = (off + bytes + 255) & ~(size_t)255;
    return p;
  };
  const size_t MT = (size_t)NB * T_SEQ;          // 4096
  ushort_t* xb   = (ushort_t*)alloc(MT * DMODEL * 2);
  ushort_t* wab  = (ushort_t*)alloc((size_t)3 * DMODEL * DMODEL * 2);
  ushort_t* wpb  = (ushort_t*)alloc((size_t)DMODEL * DMODEL * 2);
  ushort_t* q_t  = (ushort_t*)alloc(MT * DMODEL * 2);
  ushort_t* k_t  = (ushort_t*)alloc(MT * DMODEL * 2);
  ushort_t* v_t  = (ushort_t*)alloc(MT * DMODEL * 2);
  ushort_t* vtb  = (ushort_t*)alloc(MT * DMODEL * 2);
  ushort_t* yb   = (ushort_t*)alloc(MT * DMODEL * 2);
  float*    trig = (float*)alloc((size_t)T_SEQ * 64 * 2 * 4);
  (void)ws_size; (void)n_in; (void)in_sizes; (void)out_size;

  {  // converts
    int n8x = (int)(MT * DMODEL / 8);
    hipLaunchKernelGGL(cvt_f32_bf16, dim3((n8x + 255) / 256), dim3(256), 0, stream, x, xb, n8x);
    int n8a = (int)((size_t)3 * DMODEL * DMODEL / 8);
    hipLaunchKernelGGL(cvt_f32_bf16, dim3((n8a + 255) / 256), dim3(256), 0, stream, w_attn, wab, n8a);
    int n8p = (int)((size_t)DMODEL * DMODEL / 8);
    hipLaunchKernelGGL(cvt_f32_bf16, dim3((n8p + 255) / 256), dim3(256), 0, stream, w_proj, wpb, n8p);
  }
  hipLaunchKernelGGL(trig_init, dim3(T_SEQ * 64 / 256), dim3(256), 0, stream, trig);

  // QKV projection, scatter into head-major q/k/v
  hipLaunchKernelGGL((gemm_bt<1>), dim3(3 * DMODEL / 128, MT / 128), dim3(256), 0, stream,
                     xb, wab, (float*)nullptr, q_t, k_t, v_t,
                     (int)MT, 3 * DMODEL, DMODEL);

  hipLaunchKernelGGL(rope_kernel, dim3(NB * T_SEQ * NH * 16 / 256), dim3(256), 0, stream,
                     q_t, k_t, trig);

  hipLaunchKernelGGL(v_transpose, dim3(T_SEQ / 64, NB * NH), dim3(256), 0, stream, v_t, vtb);

  hipLaunchKernelGGL(flash_attn, dim3(T_SEQ / 64, NB * NH), dim3(256), 0, stream,
                     q_t, k_t, vtb, yb);

  // output projection
  hipLaunchKernelGGL((gemm_bt<0>), dim3(DMODEL / 128, MT / 128), dim3(256), 0, stream,
                     yb, wpb, out, (ushort_t*)nullptr, (ushort_t*)nullptr, (ushort_t*)nullptr,
                     (int)MT, DMODEL, DMODEL);
}

// Round 2
// 405.267 us; speedup vs baseline: 1.0294x; 1.0294x over previous
//
#include <hip/hip_runtime.h>
#include <hip/hip_bf16.h>

#define T_SEQ 2048
#define DMODEL 2048
#define NB 2
#define NH 16
#define HD 128

typedef __attribute__((ext_vector_type(8))) short short8;
typedef __attribute__((ext_vector_type(4))) float f32x4;
typedef unsigned short ushort_t;

__device__ inline ushort_t f2bf(float f) {
  union { float f; unsigned u; } v; v.f = f;
  unsigned r = v.u + 0x7fffu + ((v.u >> 16) & 1u);
  return (ushort_t)(r >> 16);
}
__device__ inline float bf2f(ushort_t u) {
  union { unsigned u; float f; } v; v.u = ((unsigned)u) << 16;
  return v.f;
}

__device__ inline void gload16(const void* g, void* l) {
  __builtin_amdgcn_global_load_lds(
      (const __attribute__((address_space(1))) unsigned*)g,
      (__attribute__((address_space(3))) unsigned*)l, 16, 0, 0);
}

// ---------------- fp32 -> bf16 convert, 8 elems/thread ----------------
__global__ void cvt_f32_bf16(const float* __restrict__ src, ushort_t* __restrict__ dst, int n8) {
  int i = blockIdx.x * blockDim.x + threadIdx.x;
  if (i >= n8) return;
  const float4* s = (const float4*)src + (size_t)i * 2;
  float4 a = s[0], b = s[1];
  short8 o;
  o[0] = (short)f2bf(a.x); o[1] = (short)f2bf(a.y);
  o[2] = (short)f2bf(a.z); o[3] = (short)f2bf(a.w);
  o[4] = (short)f2bf(b.x); o[5] = (short)f2bf(b.y);
  o[6] = (short)f2bf(b.z); o[7] = (short)f2bf(b.w);
  *((short8*)dst + i) = o;
}

// ---------------- cos/sin table: trig[t*128 + i*2] = cos, +1 = sin ----
__global__ void trig_init(float* __restrict__ trig) {
  int idx = blockIdx.x * blockDim.x + threadIdx.x;  // T*64
  if (idx >= T_SEQ * 64) return;
  int i = idx & 63, t = idx >> 6;
  float inv = __expf(-(float)i * (9.210340371976184f / 64.0f));
  float f = (float)t * inv;
  trig[idx * 2]     = cosf(f);
  trig[idx * 2 + 1] = sinf(f);
}

// ---------------- RoPE in-place on q,k ([B][H][T][128] bf16) ----------
__global__ void rope_kernel(ushort_t* __restrict__ q, ushort_t* __restrict__ k,
                            const float* __restrict__ trig) {
  int idx = blockIdx.x * blockDim.x + threadIdx.x;  // NB*T*NH*16
  int i8 = idx & 15;
  int h  = (idx >> 4) & 15;
  int t  = (idx >> 8) & (T_SEQ - 1);
  int b  = idx >> 19;
  size_t base = ((size_t)((b * NH + h) * T_SEQ + t)) * HD + i8 * 8;
  const float4* tr = (const float4*)(trig + t * 128 + i8 * 8);
  float4 t0 = tr[0], t1 = tr[1];
  float c[4] = { t0.x, t0.z, t1.x, t1.z };
  float s[4] = { t0.y, t0.w, t1.y, t1.w };
  short8 vq = *(short8*)(q + base);
  short8 vk = *(short8*)(k + base);
  short8 oq, ok;
#pragma unroll
  for (int j = 0; j < 4; ++j) {
    float x1 = bf2f((ushort_t)vq[2*j]), x2 = bf2f((ushort_t)vq[2*j+1]);
    oq[2*j]   = (short)f2bf(x1 * c[j] - x2 * s[j]);
    oq[2*j+1] = (short)f2bf(x1 * s[j] + x2 * c[j]);
    x1 = bf2f((ushort_t)vk[2*j]); x2 = bf2f((ushort_t)vk[2*j+1]);
    ok[2*j]   = (short)f2bf(x1 * c[j] - x2 * s[j]);
    ok[2*j+1] = (short)f2bf(x1 * s[j] + x2 * c[j]);
  }
  *(short8*)(q + base) = oq;
  *(short8*)(k + base) = ok;
}

// ---------------- V transpose: [B][H][T][128] -> [B][H][128][T] -------
__global__ __launch_bounds__(256)
void v_transpose(const ushort_t* __restrict__ v, ushort_t* __restrict__ vt) {
  __shared__ __align__(16) ushort_t L[64][136];
  int bh = blockIdx.y;
  int t0 = blockIdx.x * 64;
  int tid = threadIdx.x;
  int row = tid >> 2, c0 = (tid & 3) * 32;
  const ushort_t* src = v + ((size_t)bh * T_SEQ + t0 + row) * HD + c0;
#pragma unroll
  for (int j = 0; j < 4; ++j)
    *(short8*)&L[row][c0 + j * 8] = *(const short8*)(src + j * 8);
  __syncthreads();
  int d = tid >> 1, tc = (tid & 1) * 32;
  union { ushort_t u[32]; short8 v8[4]; } buf;
#pragma unroll
  for (int j = 0; j < 32; ++j) buf.u[j] = L[tc + j][d];
  ushort_t* dst = vt + ((size_t)bh * HD + d) * T_SEQ + t0 + tc;
#pragma unroll
  for (int j = 0; j < 4; ++j) *(short8*)(dst + j * 8) = buf.v8[j];
}

// ---------------- GEMM C = A * Bt^T (bf16 in, fp32 acc) ---------------
template <int EPI>
__global__ __launch_bounds__(256)
void gemm_bt(const ushort_t* __restrict__ A, const ushort_t* __restrict__ Bt,
             float* __restrict__ C, ushort_t* __restrict__ q_t,
             ushort_t* __restrict__ k_t, ushort_t* __restrict__ v_t,
             int M, int N, int K) {
  __shared__ __align__(16) ushort_t As[128 * 32];
  __shared__ __align__(16) ushort_t Bs[128 * 32];
  int tid = threadIdx.x, lane = tid & 63, w = tid >> 6;
  int wm = w >> 1, wn = w & 1;
  int li = lane & 15, lg = lane >> 4;
  int tile_n = blockIdx.x * 128, tile_m = blockIdx.y * 128;
  f32x4 acc[4][4] = {};
  int arow = lane >> 2, acol = (lane & 3) * 8;
  const ushort_t* Ag = A + (size_t)tile_m * K;
  const ushort_t* Bg = Bt + (size_t)tile_n * K;
  for (int k0 = 0; k0 < K; k0 += 32) {
#pragma unroll
    for (int i = 0; i < 2; ++i) {
      int blk = w * 2 + i;
      gload16(Ag + (size_t)(blk * 16 + arow) * K + k0 + acol, &As[blk * 512]);
      gload16(Bg + (size_t)(blk * 16 + arow) * K + k0 + acol, &Bs[blk * 512]);
    }
    __syncthreads();
    short8 af[4], bf[4];
#pragma unroll
    for (int mi = 0; mi < 4; ++mi)
      af[mi] = *(const short8*)&As[(wm * 64 + mi * 16 + li) * 32 + lg * 8];
#pragma unroll
    for (int ni = 0; ni < 4; ++ni)
      bf[ni] = *(const short8*)&Bs[(wn * 64 + ni * 16 + li) * 32 + lg * 8];
#pragma unroll
    for (int mi = 0; mi < 4; ++mi)
#pragma unroll
      for (int ni = 0; ni < 4; ++ni)
        acc[mi][ni] = __builtin_amdgcn_mfma_f32_16x16x32_bf16(af[mi], bf[ni], acc[mi][ni], 0, 0, 0);
    __syncthreads();
  }
#pragma unroll
  for (int mi = 0; mi < 4; ++mi) {
    int row = tile_m + wm * 64 + mi * 16 + lg * 4;
#pragma unroll
    for (int ni = 0; ni < 4; ++ni) {
      int col = tile_n + wn * 64 + ni * 16 + li;
#pragma unroll
      for (int r = 0; r < 4; ++r) {
        float val = acc[mi][ni][r];
        if (EPI == 0) {
          C[(size_t)(row + r) * N + col] = val;
        } else {
          int m = row + r;
          int b = m >> 11, t = m & 2047;
          int sec = col >> 11, nn = col & 2047;
          int h = nn >> 7, d = nn & 127;
          ushort_t* dst = (sec == 0) ? q_t : ((sec == 1) ? k_t : v_t);
          dst[((size_t)((b * NH + h) * T_SEQ + t)) * HD + d] = f2bf(val);
        }
      }
    }
  }
}

// ---------------- Flash attention (causal), double-buffered -----------
// Q,K: [B*H][T][128] bf16 (roped). Vt: [B*H][128][T] bf16. Y: [B*T][2048] bf16.
// grid (T/64, B*H), 256 threads. Heavy-first: qt = gridDim.x-1-blockIdx.x.
// K tile swizzle: 4-bit chunk XOR (row&15); V tile: 3-bit (row&7).
__global__ __launch_bounds__(256)
void flash_attn(const ushort_t* __restrict__ Q, const ushort_t* __restrict__ Kg,
                const ushort_t* __restrict__ Vt, ushort_t* __restrict__ Y) {
  __shared__ __align__(16) ushort_t Ks[2][64 * 128];
  __shared__ __align__(16) ushort_t Vs[2][128 * 64];
  __shared__ __align__(16) ushort_t Ps[4][16 * 72];
  int tid = threadIdx.x, lane = tid & 63, w = tid >> 6;
  int li = lane & 15, lg = lane >> 4;
  int qt = (gridDim.x - 1) - blockIdx.x;  // heavy blocks dispatch first
  int bh = blockIdx.y;
  int b = bh >> 4, h = bh & 15;
  int q0 = qt * 64;
  const ushort_t* Qp = Q + (size_t)bh * T_SEQ * HD;
  const ushort_t* Kp = Kg + (size_t)bh * T_SEQ * HD;
  const ushort_t* Vp = Vt + (size_t)bh * HD * T_SEQ;

  auto stage = [&](int kv0, ushort_t* Kb, ushort_t* Vb) {
#pragma unroll
    for (int i = 0; i < 4; ++i) {
      int blk = w * 4 + i;
      {  // K: 4 rows x 256B per blk; pre-swizzled source, 4-bit XOR
        int row = blk * 4 + lg;
        int kb = (li * 16) ^ ((row & 15) << 4);
        gload16(Kp + (size_t)(kv0 + row) * HD + (kb >> 1), &Kb[blk * 512]);
      }
      {  // Vt: 8 rows x 128B per blk; 3-bit XOR
        int d = blk * 8 + (lane >> 3);
        int kb = ((lane & 7) * 16) ^ ((d & 7) << 4);
        gload16(Vp + (size_t)d * T_SEQ + kv0 + (kb >> 1), &Vb[blk * 512]);
      }
    }
  };

  short8 qf[4];
  {
    int qrow = q0 + w * 16 + li;
#pragma unroll
    for (int ks = 0; ks < 4; ++ks)
      qf[ks] = *(const short8*)(Qp + (size_t)qrow * HD + ks * 32 + lg * 8);
  }
  f32x4 o[8] = {};
  float m_r[4], l_r[4];
#pragma unroll
  for (int r = 0; r < 4; ++r) { m_r[r] = -3e38f; l_r[r] = 0.f; }
  const float scale = 0.08838834764831845f;  // 1/sqrt(128)

  int nkt = qt + 1;
  stage(0, Ks[0], Vs[0]);
  __syncthreads();
  int cur = 0;
  for (int kt = 0; kt < nkt; ++kt) {
    if (kt + 1 < nkt) stage((kt + 1) * 64, Ks[cur ^ 1], Vs[cur ^ 1]);
    const ushort_t* Kc = Ks[cur];
    const ushort_t* Vc = Vs[cur];
    // S = Q K^T * scale
    f32x4 s[4];
    __builtin_amdgcn_s_setprio(1);
#pragma unroll
    for (int nt = 0; nt < 4; ++nt) {
      f32x4 a = {};
      int row = nt * 16 + li;
#pragma unroll
      for (int ks = 0; ks < 4; ++ks) {
        int kb = (ks * 64 + lg * 16) ^ ((row & 15) << 4);
        short8 kf = *(const short8*)&Kc[row * 128 + (kb >> 1)];
        a = __builtin_amdgcn_mfma_f32_16x16x32_bf16(qf[ks], kf, a, 0, 0, 0);
      }
#pragma unroll
      for (int r = 0; r < 4; ++r) s[nt][r] = a[r] * scale;
    }
    __builtin_amdgcn_s_setprio(0);
    if (kt == nkt - 1) {
#pragma unroll
      for (int nt = 0; nt < 4; ++nt)
#pragma unroll
        for (int r = 0; r < 4; ++r)
          if (nt * 16 + li > w * 16 + lg * 4 + r) s[nt][r] = -3e30f;
    }
    // row max (16-lane butterfly)
    float mx[4];
#pragma unroll
    for (int r = 0; r < 4; ++r)
      mx[r] = fmaxf(fmaxf(s[0][r], s[1][r]), fmaxf(s[2][r], s[3][r]));
#pragma unroll
    for (int msk = 1; msk <= 8; msk <<= 1)
#pragma unroll
      for (int r = 0; r < 4; ++r)
        mx[r] = fmaxf(mx[r], __shfl_xor(mx[r], msk));
    float alpha[4], mn[4];
#pragma unroll
    for (int r = 0; r < 4; ++r) {
      mn[r] = fmaxf(m_r[r], mx[r]);
      alpha[r] = __expf(m_r[r] - mn[r]);
      m_r[r] = mn[r];
    }
    float p[4][4], rs[4];
#pragma unroll
    for (int r = 0; r < 4; ++r) rs[r] = 0.f;
#pragma unroll
    for (int nt = 0; nt < 4; ++nt)
#pragma unroll
      for (int r = 0; r < 4; ++r) {
        p[nt][r] = __expf(s[nt][r] - mn[r]);
        rs[r] += p[nt][r];
      }
#pragma unroll
    for (int msk = 1; msk <= 8; msk <<= 1)
#pragma unroll
      for (int r = 0; r < 4; ++r)
        rs[r] += __shfl_xor(rs[r], msk);
#pragma unroll
    for (int r = 0; r < 4; ++r) l_r[r] = l_r[r] * alpha[r] + rs[r];
#pragma unroll
    for (int ot = 0; ot < 8; ++ot)
#pragma unroll
      for (int r = 0; r < 4; ++r) o[ot][r] *= alpha[r];
    // P -> per-wave LDS (C-frag -> A-frag layout convert)
#pragma unroll
    for (int nt = 0; nt < 4; ++nt)
#pragma unroll
      for (int r = 0; r < 4; ++r)
        Ps[w][(lg * 4 + r) * 72 + nt * 16 + li] = f2bf(p[nt][r]);
    asm volatile("s_waitcnt lgkmcnt(0)" ::: "memory");
    short8 pf[2];
#pragma unroll
    for (int ks = 0; ks < 2; ++ks)
      pf[ks] = *(const short8*)&Ps[w][li * 72 + ks * 32 + lg * 8];
    __builtin_amdgcn_s_setprio(1);
#pragma unroll
    for (int ot = 0; ot < 8; ++ot) {
      int vrow = ot * 16 + li;
#pragma unroll
      for (int ks = 0; ks < 2; ++ks) {
        int kb = (ks * 64 + lg * 16) ^ ((vrow & 7) << 4);
        short8 vf = *(const short8*)&Vc[vrow * 64 + (kb >> 1)];
        o[ot] = __builtin_amdgcn_mfma_f32_16x16x32_bf16(pf[ks], vf, o[ot], 0, 0, 0);
      }
    }
    __builtin_amdgcn_s_setprio(0);
    __syncthreads();
    cur ^= 1;
  }
  float inv_l[4];
#pragma unroll
  for (int r = 0; r < 4; ++r) inv_l[r] = 1.f / l_r[r];
#pragma unroll
  for (int ot = 0; ot < 8; ++ot) {
    int col = h * HD + ot * 16 + li;
#pragma unroll
    for (int r = 0; r < 4; ++r) {
      int t = q0 + w * 16 + lg * 4 + r;
      Y[((size_t)(b * T_SEQ + t)) * DMODEL + col] = f2bf(o[ot][r] * inv_l[r]);
    }
  }
}

extern "C" void kernel_launch(void* const* d_in, const int* in_sizes, int n_in,
                              void* d_out, int out_size, void* d_ws, size_t ws_size,
                              hipStream_t stream) {
  const float* x      = (const float*)d_in[0];
  const float* w_attn = (const float*)d_in[1];
  const float* w_proj = (const float*)d_in[2];
  float* out = (float*)d_out;

  char* ws = (char*)d_ws;
  size_t off = 0;
  auto alloc = [&](size_t bytes) -> void* {
    void* p = ws + off;
    off = (off + bytes + 255) & ~(size_t)255;
    return p;
  };
  const size_t MT = (size_t)NB * T_SEQ;          // 4096
  ushort_t* xb   = (ushort_t*)alloc(MT * DMODEL * 2);
  ushort_t* wab  = (ushort_t*)alloc((size_t)3 * DMODEL * DMODEL * 2);
  ushort_t* wpb  = (ushort_t*)alloc((size_t)DMODEL * DMODEL * 2);
  ushort_t* q_t  = (ushort_t*)alloc(MT * DMODEL * 2);
  ushort_t* k_t  = (ushort_t*)alloc(MT * DMODEL * 2);
  ushort_t* v_t  = (ushort_t*)alloc(MT * DMODEL * 2);
  ushort_t* vtb  = (ushort_t*)alloc(MT * DMODEL * 2);
  ushort_t* yb   = (ushort_t*)alloc(MT * DMODEL * 2);
  float*    trig = (float*)alloc((size_t)T_SEQ * 64 * 2 * 4);
  (void)ws_size; (void)n_in; (void)in_sizes; (void)out_size;

  {  // converts
    int n8x = (int)(MT * DMODEL / 8);
    hipLaunchKernelGGL(cvt_f32_bf16, dim3((n8x + 255) / 256), dim3(256), 0, stream, x, xb, n8x);
    int n8a = (int)((size_t)3 * DMODEL * DMODEL / 8);
    hipLaunchKernelGGL(cvt_f32_bf16, dim3((n8a + 255) / 256), dim3(256), 0, stream, w_attn, wab, n8a);
    int n8p = (int)((size_t)DMODEL * DMODEL / 8);
    hipLaunchKernelGGL(cvt_f32_bf16, dim3((n8p + 255) / 256), dim3(256), 0, stream, w_proj, wpb, n8p);
  }
  hipLaunchKernelGGL(trig_init, dim3(T_SEQ * 64 / 256), dim3(256), 0, stream, trig);

  hipLaunchKernelGGL((gemm_bt<1>), dim3(3 * DMODEL / 128, MT / 128), dim3(256), 0, stream,
                     xb, wab, (float*)nullptr, q_t, k_t, v_t,
                     (int)MT, 3 * DMODEL, DMODEL);

  hipLaunchKernelGGL(rope_kernel, dim3(NB * T_SEQ * NH * 16 / 256), dim3(256), 0, stream,
                     q_t, k_t, trig);

  hipLaunchKernelGGL(v_transpose, dim3(T_SEQ / 64, NB * NH), dim3(256), 0, stream, v_t, vtb);

  hipLaunchKernelGGL(flash_attn, dim3(T_SEQ / 64, NB * NH), dim3(256), 0, stream,
                     q_t, k_t, vtb, yb);

  hipLaunchKernelGGL((gemm_bt<0>), dim3(DMODEL / 128, MT / 128), dim3(256), 0, stream,
                     yb, wpb, out, (ushort_t*)nullptr, (ushort_t*)nullptr, (ushort_t*)nullptr,
                     (int)MT, DMODEL, DMODEL);
}

// Round 3
// 322.038 us; speedup vs baseline: 1.2954x; 1.2584x over previous
//
#include <hip/hip_runtime.h>
#include <hip/hip_bf16.h>

#define T_SEQ 2048
#define DMODEL 2048
#define NB 2
#define NH 16
#define HD 128

typedef __attribute__((ext_vector_type(8))) short short8;
typedef __attribute__((ext_vector_type(4))) float f32x4;
typedef __attribute__((ext_vector_type(16))) float f32x16;
typedef unsigned short ushort_t;

__device__ inline ushort_t f2bf(float f) {
  union { float f; unsigned u; } v; v.f = f;
  unsigned r = v.u + 0x7fffu + ((v.u >> 16) & 1u);
  return (ushort_t)(r >> 16);
}
__device__ inline float bf2f(ushort_t u) {
  union { unsigned u; float f; } v; v.u = ((unsigned)u) << 16;
  return v.f;
}
__device__ inline unsigned pk2(float x, float y) {
  union { __hip_bfloat162 h; unsigned u; } c;
  c.h = __float22bfloat162_rn(float2{x, y});
  return c.u;
}
__device__ inline float fexp2(float x) {
  float r;
  asm("v_exp_f32 %0, %1" : "=v"(r) : "v"(x));
  return r;
}

__device__ inline void gload16(const void* g, void* l) {
  __builtin_amdgcn_global_load_lds(
      (const __attribute__((address_space(1))) unsigned*)g,
      (__attribute__((address_space(3))) unsigned*)l, 16, 0, 0);
}

// ---------------- fp32 -> bf16 convert, 8 elems/thread ----------------
__global__ void cvt_f32_bf16(const float* __restrict__ src, ushort_t* __restrict__ dst, int n8) {
  int i = blockIdx.x * blockDim.x + threadIdx.x;
  if (i >= n8) return;
  const float4* s = (const float4*)src + (size_t)i * 2;
  float4 a = s[0], b = s[1];
  short8 o;
  o[0] = (short)f2bf(a.x); o[1] = (short)f2bf(a.y);
  o[2] = (short)f2bf(a.z); o[3] = (short)f2bf(a.w);
  o[4] = (short)f2bf(b.x); o[5] = (short)f2bf(b.y);
  o[6] = (short)f2bf(b.z); o[7] = (short)f2bf(b.w);
  *((short8*)dst + i) = o;
}

// ---------------- cos/sin table ----------------
__global__ void trig_init(float* __restrict__ trig) {
  int idx = blockIdx.x * blockDim.x + threadIdx.x;  // T*64
  if (idx >= T_SEQ * 64) return;
  int i = idx & 63, t = idx >> 6;
  float inv = __expf(-(float)i * (9.210340371976184f / 64.0f));
  float f = (float)t * inv;
  trig[idx * 2]     = cosf(f);
  trig[idx * 2 + 1] = sinf(f);
}

// ---------------- RoPE in-place on q,k ([B][H][T][128] bf16) ----------
__global__ void rope_kernel(ushort_t* __restrict__ q, ushort_t* __restrict__ k,
                            const float* __restrict__ trig) {
  int idx = blockIdx.x * blockDim.x + threadIdx.x;  // NB*T*NH*16
  int i8 = idx & 15;
  int h  = (idx >> 4) & 15;
  int t  = (idx >> 8) & (T_SEQ - 1);
  int b  = idx >> 19;
  size_t base = ((size_t)((b * NH + h) * T_SEQ + t)) * HD + i8 * 8;
  const float4* tr = (const float4*)(trig + t * 128 + i8 * 8);
  float4 t0 = tr[0], t1 = tr[1];
  float c[4] = { t0.x, t0.z, t1.x, t1.z };
  float s[4] = { t0.y, t0.w, t1.y, t1.w };
  short8 vq = *(short8*)(q + base);
  short8 vk = *(short8*)(k + base);
  short8 oq, ok;
#pragma unroll
  for (int j = 0; j < 4; ++j) {
    float x1 = bf2f((ushort_t)vq[2*j]), x2 = bf2f((ushort_t)vq[2*j+1]);
    oq[2*j]   = (short)f2bf(x1 * c[j] - x2 * s[j]);
    oq[2*j+1] = (short)f2bf(x1 * s[j] + x2 * c[j]);
    x1 = bf2f((ushort_t)vk[2*j]); x2 = bf2f((ushort_t)vk[2*j+1]);
    ok[2*j]   = (short)f2bf(x1 * c[j] - x2 * s[j]);
    ok[2*j+1] = (short)f2bf(x1 * s[j] + x2 * c[j]);
  }
  *(short8*)(q + base) = oq;
  *(short8*)(k + base) = ok;
}

// ---------------- V transpose: [B][H][T][128] -> [B][H][128][T] -------
__global__ __launch_bounds__(256)
void v_transpose(const ushort_t* __restrict__ v, ushort_t* __restrict__ vt) {
  __shared__ __align__(16) ushort_t L[64][136];
  int bh = blockIdx.y;
  int t0 = blockIdx.x * 64;
  int tid = threadIdx.x;
  int row = tid >> 2, c0 = (tid & 3) * 32;
  const ushort_t* src = v + ((size_t)bh * T_SEQ + t0 + row) * HD + c0;
#pragma unroll
  for (int j = 0; j < 4; ++j)
    *(short8*)&L[row][c0 + j * 8] = *(const short8*)(src + j * 8);
  __syncthreads();
  int d = tid >> 1, tc = (tid & 1) * 32;
  union { ushort_t u[32]; short8 v8[4]; } buf;
#pragma unroll
  for (int j = 0; j < 32; ++j) buf.u[j] = L[tc + j][d];
  ushort_t* dst = vt + ((size_t)bh * HD + d) * T_SEQ + t0 + tc;
#pragma unroll
  for (int j = 0; j < 4; ++j) *(short8*)(dst + j * 8) = buf.v8[j];
}

// ---------------- GEMM C = A * Bt^T (bf16 in, fp32 acc) ---------------
template <int EPI>
__global__ __launch_bounds__(256)
void gemm_bt(const ushort_t* __restrict__ A, const ushort_t* __restrict__ Bt,
             float* __restrict__ C, ushort_t* __restrict__ q_t,
             ushort_t* __restrict__ k_t, ushort_t* __restrict__ v_t,
             int M, int N, int K) {
  __shared__ __align__(16) ushort_t As[128 * 32];
  __shared__ __align__(16) ushort_t Bs[128 * 32];
  int tid = threadIdx.x, lane = tid & 63, w = tid >> 6;
  int wm = w >> 1, wn = w & 1;
  int li = lane & 15, lg = lane >> 4;
  int tile_n = blockIdx.x * 128, tile_m = blockIdx.y * 128;
  f32x4 acc[4][4] = {};
  int arow = lane >> 2, acol = (lane & 3) * 8;
  const ushort_t* Ag = A + (size_t)tile_m * K;
  const ushort_t* Bg = Bt + (size_t)tile_n * K;
  for (int k0 = 0; k0 < K; k0 += 32) {
#pragma unroll
    for (int i = 0; i < 2; ++i) {
      int blk = w * 2 + i;
      gload16(Ag + (size_t)(blk * 16 + arow) * K + k0 + acol, &As[blk * 512]);
      gload16(Bg + (size_t)(blk * 16 + arow) * K + k0 + acol, &Bs[blk * 512]);
    }
    __syncthreads();
    short8 af[4], bfr[4];
#pragma unroll
    for (int mi = 0; mi < 4; ++mi)
      af[mi] = *(const short8*)&As[(wm * 64 + mi * 16 + li) * 32 + lg * 8];
#pragma unroll
    for (int ni = 0; ni < 4; ++ni)
      bfr[ni] = *(const short8*)&Bs[(wn * 64 + ni * 16 + li) * 32 + lg * 8];
#pragma unroll
    for (int mi = 0; mi < 4; ++mi)
#pragma unroll
      for (int ni = 0; ni < 4; ++ni)
        acc[mi][ni] = __builtin_amdgcn_mfma_f32_16x16x32_bf16(af[mi], bfr[ni], acc[mi][ni], 0, 0, 0);
    __syncthreads();
  }
#pragma unroll
  for (int mi = 0; mi < 4; ++mi) {
    int row = tile_m + wm * 64 + mi * 16 + lg * 4;
#pragma unroll
    for (int ni = 0; ni < 4; ++ni) {
      int col = tile_n + wn * 64 + ni * 16 + li;
#pragma unroll
      for (int r = 0; r < 4; ++r) {
        float val = acc[mi][ni][r];
        if (EPI == 0) {
          C[(size_t)(row + r) * N + col] = val;
        } else {
          int m = row + r;
          int b = m >> 11, t = m & 2047;
          int sec = col >> 11, nn = col & 2047;
          int h = nn >> 7, d = nn & 127;
          ushort_t* dst = (sec == 0) ? q_t : ((sec == 1) ? k_t : v_t);
          dst[((size_t)((b * NH + h) * T_SEQ + t)) * HD + d] = f2bf(val);
        }
      }
    }
  }
}

// ---------------- Flash attention (causal), swapped-QK 32x32 ----------
// Q,K: [B*H][T][128] bf16 (roped). Vt: [B*H][128][T] bf16. Y: [B*T][2048] bf16.
// Block: 256 thr (4 waves), QBLK=128 (32 q-rows/wave), KVBLK=64.
// S^T = mfma32(K, Q): lane owns q-row (lane&31); softmax fully in-register.
__global__ __launch_bounds__(256, 2)
void flash_attn(const ushort_t* __restrict__ Q, const ushort_t* __restrict__ Kg,
                const ushort_t* __restrict__ Vt, ushort_t* __restrict__ Y) {
  __shared__ __align__(16) ushort_t ldsK[2 * 64 * 128];   // 32KB, 2 buf
  __shared__ __align__(16) ushort_t ldsV[2 * 128 * 64];   // 32KB, 2 buf
  int tid = threadIdx.x, lane = tid & 63, w = tid >> 6;
  int hi = lane >> 5, l31 = lane & 31;
  // paired causal balance: dispatch-half by>=16 gets mirrored qi
  int qi = (blockIdx.y & 16) ? (15 - (int)blockIdx.x) : (int)blockIdx.x;
  int bh = blockIdx.y;
  int b = bh >> 4, h = bh & 15;
  int q0 = qi * 128;
  const ushort_t* Qp = Q + (size_t)bh * T_SEQ * HD;
  const ushort_t* Kp = Kg + (size_t)bh * T_SEQ * HD;
  const ushort_t* Vp = Vt + (size_t)bh * HD * T_SEQ;

  int qg = q0 + w * 32 + l31;     // this lane's q row
  int qmaxw = q0 + w * 32 + 31;   // wave-uniform

  auto stage = [&](int kv0, int bsel) {
    ushort_t* Kb = ldsK + bsel * 8192;
    ushort_t* Vb = ldsV + bsel * 8192;
#pragma unroll
    for (int p = 0; p < 4; ++p) {
      int c = p * 256 + w * 64 + lane;
      {  // K tile [64 rows][16 chunks], swizzle chunk ^= row&15
        int row = c >> 4, cc = c & 15;
        int sc = cc ^ (row & 15);
        gload16(Kp + (size_t)(kv0 + row) * HD + sc * 8, Kb + (p * 256 + w * 64) * 8);
      }
      {  // Vt tile [128 rows][8 chunks], swizzle chunk ^= row&7
        int d = c >> 3, cc = c & 7;
        int sc = cc ^ (d & 7);
        gload16(Vp + (size_t)d * T_SEQ + kv0 + sc * 8, Vb + (p * 256 + w * 64) * 8);
      }
    }
  };

  // Q fragments: B-operand, lane&31 = q col, k = d = ds*16 + hi*8 + e
  short8 qf[8];
#pragma unroll
  for (int ds = 0; ds < 8; ++ds)
    qf[ds] = *(const short8*)(Qp + (size_t)qg * HD + ds * 16 + hi * 8);

  f32x16 o[4] = {};     // O^T accum: rows d = dsub*32 + regmap, col q = lane&31
  float mu = -1e30f, l = 0.f;
  const float SIG = 0.12751879523209784f;  // (1/sqrt(128)) * log2(e)

  int nkt = 2 * qi + 2;
  stage(0, 0);
  __syncthreads();
  int cur = 0;
  for (int kt = 0; kt < nkt; ++kt) {
    int kv0 = kt * 64;
    if (kt + 1 < nkt) stage((kt + 1) * 64, cur ^ 1);
    if (kv0 <= qmaxw) {
      const ushort_t* Kb = ldsK + cur * 8192;
      const ushort_t* Vb = ldsV + cur * 8192;
      // ---- S^T = K · Q^T  (two 32-kv subtiles) ----
      f32x16 sa = {}, sb = {};
      __builtin_amdgcn_s_setprio(1);
#pragma unroll
      for (int ds = 0; ds < 8; ++ds) {
        int cc = ds * 2 + hi;
        short8 k0 = *(const short8*)&Kb[l31 * 128 + ((cc ^ (l31 & 15)) * 8)];
        short8 k1 = *(const short8*)&Kb[(32 + l31) * 128 + ((cc ^ (l31 & 15)) * 8)];
        sa = __builtin_amdgcn_mfma_f32_32x32x16_bf16(k0, qf[ds], sa, 0, 0, 0);
        sb = __builtin_amdgcn_mfma_f32_32x32x16_bf16(k1, qf[ds], sb, 0, 0, 0);
      }
      __builtin_amdgcn_s_setprio(0);
      // ---- in-register softmax (lane owns q-row l31, 32 kv values) ----
      float p[32];
#pragma unroll
      for (int r = 0; r < 16; ++r) { p[r] = sa[r] * SIG; p[16 + r] = sb[r] * SIG; }
      if (kv0 + 63 > qmaxw - 31 + (l31 - l31)) {  // wave-uniform: kv0+63 > qminw
        if (kv0 + 63 > q0 + w * 32) {
#pragma unroll
          for (int r = 0; r < 16; ++r) {
            int loc = (r & 3) + 8 * (r >> 2) + 4 * hi;
            if (kv0 + loc > qg)      p[r]      = -3e38f;
            if (kv0 + 32 + loc > qg) p[16 + r] = -3e38f;
          }
        }
      }
      // tree max (depth 5)
      float tm[16];
#pragma unroll
      for (int i = 0; i < 16; ++i) tm[i] = fmaxf(p[i], p[i + 16]);
#pragma unroll
      for (int st = 8; st >= 1; st >>= 1)
#pragma unroll
        for (int i = 0; i < 8; ++i)
          if (i < st) tm[i] = fmaxf(tm[i], tm[i + st]);
      float pmax = fmaxf(tm[0], __shfl_xor(tm[0], 32));
      // defer-max (T13)
      bool resc = !__all(pmax <= mu + 11.0f);
      if (resc) {
        float munew = fmaxf(mu, pmax);
        float alpha = fexp2(mu - munew);
        mu = munew;
        l *= alpha;
#pragma unroll
        for (int dsub = 0; dsub < 4; ++dsub)
#pragma unroll
          for (int r = 0; r < 16; ++r) o[dsub][r] *= alpha;
      }
#pragma unroll
      for (int i = 0; i < 32; ++i) p[i] = fexp2(p[i] - mu);
      // tree sum
      float ts[16];
#pragma unroll
      for (int i = 0; i < 16; ++i) ts[i] = p[i] + p[i + 16];
#pragma unroll
      for (int st = 8; st >= 1; st >>= 1)
#pragma unroll
        for (int i = 0; i < 8; ++i)
          if (i < st) ts[i] += ts[i + st];
      l += ts[0] + __shfl_xor(ts[0], 32);
      // ---- P -> bf16 B-frags (T12 half-swap) + PV ----
      __builtin_amdgcn_s_setprio(1);
#pragma unroll
      for (int s = 0; s < 4; ++s) {
        int rb = (s >> 1) * 16 + (s & 1) * 8;
        unsigned a0 = pk2(p[rb + 0], p[rb + 1]);
        unsigned a1 = pk2(p[rb + 2], p[rb + 3]);
        unsigned a2 = pk2(p[rb + 4], p[rb + 5]);
        unsigned a3 = pk2(p[rb + 6], p[rb + 7]);
        unsigned sa0 = (unsigned)__shfl_xor((int)a0, 32);
        unsigned sa1 = (unsigned)__shfl_xor((int)a1, 32);
        unsigned sa2 = (unsigned)__shfl_xor((int)a2, 32);
        unsigned sa3 = (unsigned)__shfl_xor((int)a3, 32);
        union { unsigned u[4]; short8 s8; } pf;
        pf.u[0] = hi ? sa2 : a0;
        pf.u[1] = hi ? sa3 : a1;
        pf.u[2] = hi ? a2 : sa0;
        pf.u[3] = hi ? a3 : sa1;
#pragma unroll
        for (int dsub = 0; dsub < 4; ++dsub) {
          int row = dsub * 32 + l31;
          short8 vf = *(const short8*)&Vb[row * 64 + (((2 * s + hi) ^ (row & 7)) * 8)];
          o[dsub] = __builtin_amdgcn_mfma_f32_32x32x16_bf16(vf, pf.s8, o[dsub], 0, 0, 0);
        }
      }
      __builtin_amdgcn_s_setprio(0);
    }
    __syncthreads();
    cur ^= 1;
  }
  // ---- epilogue: normalize, transpose O^T via LDS, coalesced store ----
  float invl = 1.f / l;
#pragma unroll
  for (int dsub = 0; dsub < 4; ++dsub)
#pragma unroll
    for (int r = 0; r < 16; ++r) o[dsub][r] *= invl;
  // write per-warp 32q x 128d bf16 region into ldsK (chunk-swizzled by q)
#pragma unroll
  for (int dsub = 0; dsub < 4; ++dsub)
#pragma unroll
    for (int r = 0; r < 16; r += 2) {
      int d0 = dsub * 32 + (r & 3) + 8 * (r >> 2) + 4 * hi;
      unsigned u = pk2(o[dsub][r], o[dsub][r + 1]);
      *(unsigned*)&ldsK[w * 4096 + l31 * 128 + (((d0 >> 3) ^ (l31 & 15)) * 8) + (d0 & 7)] = u;
    }
  __syncthreads();
#pragma unroll
  for (int rep = 0; rep < 8; ++rep) {
    int idx = rep * 256 + tid;
    int qg2 = idx >> 4, c = idx & 15;
    int wv2 = qg2 >> 5, ql = qg2 & 31;
    short8 val = *(const short8*)&ldsK[wv2 * 4096 + ql * 128 + ((c ^ (ql & 15)) * 8)];
    *(short8*)(Y + ((size_t)(b * T_SEQ + q0 + qg2)) * DMODEL + h * HD + c * 8) = val;
  }
}

extern "C" void kernel_launch(void* const* d_in, const int* in_sizes, int n_in,
                              void* d_out, int out_size, void* d_ws, size_t ws_size,
                              hipStream_t stream) {
  const float* x      = (const float*)d_in[0];
  const float* w_attn = (const float*)d_in[1];
  const float* w_proj = (const float*)d_in[2];
  float* out = (float*)d_out;

  char* ws = (char*)d_ws;
  size_t off = 0;
  auto alloc = [&](size_t bytes) -> void* {
    void* p = ws + off;
    off = (off + bytes + 255) & ~(size_t)255;
    return p;
  };
  const size_t MT = (size_t)NB * T_SEQ;          // 4096
  ushort_t* xb   = (ushort_t*)alloc(MT * DMODEL * 2);
  ushort_t* wab  = (ushort_t*)alloc((size_t)3 * DMODEL * DMODEL * 2);
  ushort_t* wpb  = (ushort_t*)alloc((size_t)DMODEL * DMODEL * 2);
  ushort_t* q_t  = (ushort_t*)alloc(MT * DMODEL * 2);
  ushort_t* k_t  = (ushort_t*)alloc(MT * DMODEL * 2);
  ushort_t* v_t  = (ushort_t*)alloc(MT * DMODEL * 2);
  ushort_t* vtb  = (ushort_t*)alloc(MT * DMODEL * 2);
  ushort_t* yb   = (ushort_t*)alloc(MT * DMODEL * 2);
  float*    trig = (float*)alloc((size_t)T_SEQ * 64 * 2 * 4);
  (void)ws_size; (void)n_in; (void)in_sizes; (void)out_size;

  {  // converts
    int n8x = (int)(MT * DMODEL / 8);
    hipLaunchKernelGGL(cvt_f32_bf16, dim3((n8x + 255) / 256), dim3(256), 0, stream, x, xb, n8x);
    int n8a = (int)((size_t)3 * DMODEL * DMODEL / 8);
    hipLaunchKernelGGL(cvt_f32_bf16, dim3((n8a + 255) / 256), dim3(256), 0, stream, w_attn, wab, n8a);
    int n8p = (int)((size_t)DMODEL * DMODEL / 8);
    hipLaunchKernelGGL(cvt_f32_bf16, dim3((n8p + 255) / 256), dim3(256), 0, stream, w_proj, wpb, n8p);
  }
  hipLaunchKernelGGL(trig_init, dim3(T_SEQ * 64 / 256), dim3(256), 0, stream, trig);

  hipLaunchKernelGGL((gemm_bt<1>), dim3(3 * DMODEL / 128, MT / 128), dim3(256), 0, stream,
                     xb, wab, (float*)nullptr, q_t, k_t, v_t,
                     (int)MT, 3 * DMODEL, DMODEL);

  hipLaunchKernelGGL(rope_kernel, dim3(NB * T_SEQ * NH * 16 / 256), dim3(256), 0, stream,
                     q_t, k_t, trig);

  hipLaunchKernelGGL(v_transpose, dim3(T_SEQ / 64, NB * NH), dim3(256), 0, stream, v_t, vtb);

  hipLaunchKernelGGL(flash_attn, dim3(T_SEQ / 128, NB * NH), dim3(256), 0, stream,
                     q_t, k_t, vtb, yb);

  hipLaunchKernelGGL((gemm_bt<0>), dim3(DMODEL / 128, MT / 128), dim3(256), 0, stream,
                     yb, wpb, out, (ushort_t*)nullptr, (ushort_t*)nullptr, (ushort_t*)nullptr,
                     (int)MT, DMODEL, DMODEL);
}

// Round 4
// 317.842 us; speedup vs baseline: 1.3125x; 1.0132x over previous
//
#include <hip/hip_runtime.h>
#include <hip/hip_bf16.h>

#define T_SEQ 2048
#define DMODEL 2048
#define NB 2
#define NH 16
#define HD 128

typedef __attribute__((ext_vector_type(8))) short short8;
typedef __attribute__((ext_vector_type(4))) float f32x4;
typedef __attribute__((ext_vector_type(16))) float f32x16;
typedef unsigned short ushort_t;

__device__ inline ushort_t f2bf(float f) {
  union { float f; unsigned u; } v; v.f = f;
  unsigned r = v.u + 0x7fffu + ((v.u >> 16) & 1u);
  return (ushort_t)(r >> 16);
}
__device__ inline float bf2f(ushort_t u) {
  union { unsigned u; float f; } v; v.u = ((unsigned)u) << 16;
  return v.f;
}
__device__ inline unsigned pk2(float x, float y) {
  union { __hip_bfloat162 h; unsigned u; } c;
  c.h = __float22bfloat162_rn(float2{x, y});
  return c.u;
}
__device__ inline float fexp2(float x) {
  float r;
  asm("v_exp_f32 %0, %1" : "=v"(r) : "v"(x));
  return r;
}

__device__ inline void gload16(const void* g, void* l) {
  __builtin_amdgcn_global_load_lds(
      (const __attribute__((address_space(1))) unsigned*)g,
      (__attribute__((address_space(3))) unsigned*)l, 16, 0, 0);
}

// ---------------- fp32 -> bf16 convert, 8 elems/thread ----------------
__global__ void cvt_f32_bf16(const float* __restrict__ src, ushort_t* __restrict__ dst, int n8) {
  int i = blockIdx.x * blockDim.x + threadIdx.x;
  if (i >= n8) return;
  const float4* s = (const float4*)src + (size_t)i * 2;
  float4 a = s[0], b = s[1];
  short8 o;
  o[0] = (short)f2bf(a.x); o[1] = (short)f2bf(a.y);
  o[2] = (short)f2bf(a.z); o[3] = (short)f2bf(a.w);
  o[4] = (short)f2bf(b.x); o[5] = (short)f2bf(b.y);
  o[6] = (short)f2bf(b.z); o[7] = (short)f2bf(b.w);
  *((short8*)dst + i) = o;
}

// ---------------- cos/sin table: trig[t*128 + i*2]=cos, +1=sin --------
__global__ void trig_init(float* __restrict__ trig) {
  int idx = blockIdx.x * blockDim.x + threadIdx.x;  // T*64
  if (idx >= T_SEQ * 64) return;
  int i = idx & 63, t = idx >> 6;
  float inv = __expf(-(float)i * (9.210340371976184f / 64.0f));
  float f = (float)t * inv;
  trig[idx * 2]     = cosf(f);
  trig[idx * 2 + 1] = sinf(f);
}

// ---------------- GEMM C = A * Bt^T (bf16 in, fp32 acc) ---------------
// EPI=0: C fp32 [M][N].
// EPI=1: QKV epilogue — q,k: fused RoPE + scatter to [B][H][T][128];
//        v: LDS-transpose, store [B][H][128][T] (vt) coalesced.
template <int EPI>
__global__ __launch_bounds__(256)
void gemm_bt(const ushort_t* __restrict__ A, const ushort_t* __restrict__ Bt,
             float* __restrict__ C, ushort_t* __restrict__ q_t,
             ushort_t* __restrict__ k_t, ushort_t* __restrict__ vt,
             const float* __restrict__ trig, int M, int N, int K) {
  __shared__ __align__(16) ushort_t smem[8192];   // As | Bs ; reused as V-transpose buf
  ushort_t* As = smem;
  ushort_t* Bs = smem + 4096;
  int tid = threadIdx.x, lane = tid & 63, w = tid >> 6;
  int wm = w >> 1, wn = w & 1;
  int li = lane & 15, lg = lane >> 4;
  int tile_n = blockIdx.x * 128, tile_m = blockIdx.y * 128;
  f32x4 acc[4][4] = {};
  int arow = lane >> 2, acol = (lane & 3) * 8;
  const ushort_t* Ag = A + (size_t)tile_m * K;
  const ushort_t* Bg = Bt + (size_t)tile_n * K;
  for (int k0 = 0; k0 < K; k0 += 32) {
#pragma unroll
    for (int i = 0; i < 2; ++i) {
      int blk = w * 2 + i;
      gload16(Ag + (size_t)(blk * 16 + arow) * K + k0 + acol, &As[blk * 512]);
      gload16(Bg + (size_t)(blk * 16 + arow) * K + k0 + acol, &Bs[blk * 512]);
    }
    __syncthreads();
    short8 af[4], bfr[4];
#pragma unroll
    for (int mi = 0; mi < 4; ++mi)
      af[mi] = *(const short8*)&As[(wm * 64 + mi * 16 + li) * 32 + lg * 8];
#pragma unroll
    for (int ni = 0; ni < 4; ++ni)
      bfr[ni] = *(const short8*)&Bs[(wn * 64 + ni * 16 + li) * 32 + lg * 8];
#pragma unroll
    for (int mi = 0; mi < 4; ++mi)
#pragma unroll
      for (int ni = 0; ni < 4; ++ni)
        acc[mi][ni] = __builtin_amdgcn_mfma_f32_16x16x32_bf16(af[mi], bfr[ni], acc[mi][ni], 0, 0, 0);
    __syncthreads();
  }

  if (EPI == 0) {
#pragma unroll
    for (int mi = 0; mi < 4; ++mi) {
      int row = tile_m + wm * 64 + mi * 16 + lg * 4;
#pragma unroll
      for (int ni = 0; ni < 4; ++ni) {
        int col = tile_n + wn * 64 + ni * 16 + li;
#pragma unroll
        for (int r = 0; r < 4; ++r)
          C[(size_t)(row + r) * N + col] = acc[mi][ni][r];
      }
    }
  } else {
    int sec = tile_n >> 11;          // block-uniform: 0=q 1=k 2=v
    int nn  = tile_n & 2047;
    int h   = nn >> 7;               // block-uniform (tile is 128-aligned)
    int bq  = tile_m >> 11;
    int t0  = tile_m & 2047;
    if (sec < 2) {
      ushort_t* dst = (sec == 0) ? q_t : k_t;
      ushort_t* base = dst + ((size_t)(bq * NH + h)) * T_SEQ * HD;
#pragma unroll
      for (int mi = 0; mi < 4; ++mi) {
        int tl = wm * 64 + mi * 16 + lg * 4;
#pragma unroll
        for (int ni = 0; ni < 4; ++ni) {
          int d = wn * 64 + ni * 16 + li;
          int fi = d >> 1;
#pragma unroll
          for (int r = 0; r < 4; ++r) {
            int t = t0 + tl + r;
            float val = acc[mi][ni][r];
            float par = __shfl_xor(val, 1);
            const float* tp = trig + t * 128 + fi * 2;
            float c = tp[0], s = tp[1];
            float out = (li & 1) ? (par * s + val * c) : (val * c - par * s);
            base[(size_t)t * HD + d] = f2bf(out);
          }
        }
      }
    } else {
      // V: transpose 128x128 (t,d) tile via LDS -> vt[bh][d][T]
      ushort_t* vbase = vt + ((size_t)(bq * NH + h)) * HD * T_SEQ;
#pragma unroll
      for (int c = 0; c < 2; ++c) {
        __syncthreads();
        if (wm == c) {
#pragma unroll
          for (int mi = 0; mi < 4; ++mi)
#pragma unroll
            for (int ni = 0; ni < 4; ++ni) {
              int d = wn * 64 + ni * 16 + li;
#pragma unroll
              for (int r = 0; r < 4; ++r) {
                int tl = mi * 16 + lg * 4 + r;   // 0..63
                smem[d * 64 + (tl ^ ((d & 7) << 3))] = f2bf(acc[mi][ni][r]);
              }
            }
        }
        __syncthreads();
#pragma unroll
        for (int j = 0; j < 4; ++j) {
          int idx = j * 256 + tid;
          int d = idx >> 3, tg = idx & 7;
          short8 val = *(const short8*)&smem[d * 64 + ((tg * 8) ^ ((d & 7) << 3))];
          *(short8*)(vbase + (size_t)d * T_SEQ + t0 + c * 64 + tg * 8) = val;
        }
      }
    }
  }
}

// ---------------- Flash attention (causal), swapped-QK 32x32 ----------
__global__ __launch_bounds__(256, 2)
void flash_attn(const ushort_t* __restrict__ Q, const ushort_t* __restrict__ Kg,
                const ushort_t* __restrict__ Vt, ushort_t* __restrict__ Y) {
  __shared__ __align__(16) ushort_t ldsK[2 * 64 * 128];   // 32KB, 2 buf
  __shared__ __align__(16) ushort_t ldsV[2 * 128 * 64];   // 32KB, 2 buf
  int tid = threadIdx.x, lane = tid & 63, w = tid >> 6;
  int hi = lane >> 5, l31 = lane & 31;
  int qi = (blockIdx.y & 16) ? (15 - (int)blockIdx.x) : (int)blockIdx.x;
  int bh = blockIdx.y;
  int b = bh >> 4, h = bh & 15;
  int q0 = qi * 128;
  const ushort_t* Qp = Q + (size_t)bh * T_SEQ * HD;
  const ushort_t* Kp = Kg + (size_t)bh * T_SEQ * HD;
  const ushort_t* Vp = Vt + (size_t)bh * HD * T_SEQ;

  int qg = q0 + w * 32 + l31;
  int qmaxw = q0 + w * 32 + 31;

  auto stage = [&](int kv0, int bsel) {
    ushort_t* Kb = ldsK + bsel * 8192;
    ushort_t* Vb = ldsV + bsel * 8192;
#pragma unroll
    for (int p = 0; p < 4; ++p) {
      int c = p * 256 + w * 64 + lane;
      {
        int row = c >> 4, cc = c & 15;
        int sc = cc ^ (row & 15);
        gload16(Kp + (size_t)(kv0 + row) * HD + sc * 8, Kb + (p * 256 + w * 64) * 8);
      }
      {
        int d = c >> 3, cc = c & 7;
        int sc = cc ^ (d & 7);
        gload16(Vp + (size_t)d * T_SEQ + kv0 + sc * 8, Vb + (p * 256 + w * 64) * 8);
      }
    }
  };

  short8 qf[8];
#pragma unroll
  for (int ds = 0; ds < 8; ++ds)
    qf[ds] = *(const short8*)(Qp + (size_t)qg * HD + ds * 16 + hi * 8);

  f32x16 o[4] = {};
  float mu = -1e30f, l = 0.f;
  const float SIG = 0.12751879523209784f;  // (1/sqrt(128)) * log2(e)

  int nkt = 2 * qi + 2;
  stage(0, 0);
  __syncthreads();
  int cur = 0;
  for (int kt = 0; kt < nkt; ++kt) {
    int kv0 = kt * 64;
    if (kt + 1 < nkt) stage((kt + 1) * 64, cur ^ 1);
    if (kv0 <= qmaxw) {
      const ushort_t* Kb = ldsK + cur * 8192;
      const ushort_t* Vb = ldsV + cur * 8192;
      f32x16 sa = {}, sb = {};
      __builtin_amdgcn_s_setprio(1);
#pragma unroll
      for (int ds = 0; ds < 8; ++ds) {
        int cc = ds * 2 + hi;
        short8 k0 = *(const short8*)&Kb[l31 * 128 + ((cc ^ (l31 & 15)) * 8)];
        short8 k1 = *(const short8*)&Kb[(32 + l31) * 128 + ((cc ^ (l31 & 15)) * 8)];
        sa = __builtin_amdgcn_mfma_f32_32x32x16_bf16(k0, qf[ds], sa, 0, 0, 0);
        sb = __builtin_amdgcn_mfma_f32_32x32x16_bf16(k1, qf[ds], sb, 0, 0, 0);
      }
      __builtin_amdgcn_s_setprio(0);
      float p[32];
#pragma unroll
      for (int r = 0; r < 16; ++r) { p[r] = sa[r] * SIG; p[16 + r] = sb[r] * SIG; }
      if (kv0 + 63 > q0 + w * 32) {
#pragma unroll
        for (int r = 0; r < 16; ++r) {
          int loc = (r & 3) + 8 * (r >> 2) + 4 * hi;
          if (kv0 + loc > qg)      p[r]      = -3e38f;
          if (kv0 + 32 + loc > qg) p[16 + r] = -3e38f;
        }
      }
      float tm[16];
#pragma unroll
      for (int i = 0; i < 16; ++i) tm[i] = fmaxf(p[i], p[i + 16]);
#pragma unroll
      for (int st = 8; st >= 1; st >>= 1)
#pragma unroll
        for (int i = 0; i < 8; ++i)
          if (i < st) tm[i] = fmaxf(tm[i], tm[i + st]);
      float pmax = fmaxf(tm[0], __shfl_xor(tm[0], 32));
      bool resc = !__all(pmax <= mu + 11.0f);
      if (resc) {
        float munew = fmaxf(mu, pmax);
        float alpha = fexp2(mu - munew);
        mu = munew;
        l *= alpha;
#pragma unroll
        for (int dsub = 0; dsub < 4; ++dsub)
#pragma unroll
          for (int r = 0; r < 16; ++r) o[dsub][r] *= alpha;
      }
#pragma unroll
      for (int i = 0; i < 32; ++i) p[i] = fexp2(p[i] - mu);
      float ts[16];
#pragma unroll
      for (int i = 0; i < 16; ++i) ts[i] = p[i] + p[i + 16];
#pragma unroll
      for (int st = 8; st >= 1; st >>= 1)
#pragma unroll
        for (int i = 0; i < 8; ++i)
          if (i < st) ts[i] += ts[i + st];
      l += ts[0] + __shfl_xor(ts[0], 32);
      __builtin_amdgcn_s_setprio(1);
#pragma unroll
      for (int s = 0; s < 4; ++s) {
        int rb = (s >> 1) * 16 + (s & 1) * 8;
        unsigned a0 = pk2(p[rb + 0], p[rb + 1]);
        unsigned a1 = pk2(p[rb + 2], p[rb + 3]);
        unsigned a2 = pk2(p[rb + 4], p[rb + 5]);
        unsigned a3 = pk2(p[rb + 6], p[rb + 7]);
        unsigned sa0 = (unsigned)__shfl_xor((int)a0, 32);
        unsigned sa1 = (unsigned)__shfl_xor((int)a1, 32);
        unsigned sa2 = (unsigned)__shfl_xor((int)a2, 32);
        unsigned sa3 = (unsigned)__shfl_xor((int)a3, 32);
        union { unsigned u[4]; short8 s8; } pf;
        pf.u[0] = hi ? sa2 : a0;
        pf.u[1] = hi ? sa3 : a1;
        pf.u[2] = hi ? a2 : sa0;
        pf.u[3] = hi ? a3 : sa1;
#pragma unroll
        for (int dsub = 0; dsub < 4; ++dsub) {
          int row = dsub * 32 + l31;
          short8 vf = *(const short8*)&Vb[row * 64 + (((2 * s + hi) ^ (row & 7)) * 8)];
          o[dsub] = __builtin_amdgcn_mfma_f32_32x32x16_bf16(vf, pf.s8, o[dsub], 0, 0, 0);
        }
      }
      __builtin_amdgcn_s_setprio(0);
    }
    __syncthreads();
    cur ^= 1;
  }
  float invl = 1.f / l;
#pragma unroll
  for (int dsub = 0; dsub < 4; ++dsub)
#pragma unroll
    for (int r = 0; r < 16; ++r) o[dsub][r] *= invl;
#pragma unroll
  for (int dsub = 0; dsub < 4; ++dsub)
#pragma unroll
    for (int r = 0; r < 16; r += 2) {
      int d0 = dsub * 32 + (r & 3) + 8 * (r >> 2) + 4 * hi;
      unsigned u = pk2(o[dsub][r], o[dsub][r + 1]);
      *(unsigned*)&ldsK[w * 4096 + l31 * 128 + (((d0 >> 3) ^ (l31 & 15)) * 8) + (d0 & 7)] = u;
    }
  __syncthreads();
#pragma unroll
  for (int rep = 0; rep < 8; ++rep) {
    int idx = rep * 256 + tid;
    int qg2 = idx >> 4, c = idx & 15;
    int wv2 = qg2 >> 5, ql = qg2 & 31;
    short8 val = *(const short8*)&ldsK[wv2 * 4096 + ql * 128 + ((c ^ (ql & 15)) * 8)];
    *(short8*)(Y + ((size_t)(b * T_SEQ + q0 + qg2)) * DMODEL + h * HD + c * 8) = val;
  }
}

extern "C" void kernel_launch(void* const* d_in, const int* in_sizes, int n_in,
                              void* d_out, int out_size, void* d_ws, size_t ws_size,
                              hipStream_t stream) {
  const float* x      = (const float*)d_in[0];
  const float* w_attn = (const float*)d_in[1];
  const float* w_proj = (const float*)d_in[2];
  float* out = (float*)d_out;

  char* ws = (char*)d_ws;
  size_t off = 0;
  auto alloc = [&](size_t bytes) -> void* {
    void* p = ws + off;
    off = (off + bytes + 255) & ~(size_t)255;
    return p;
  };
  const size_t MT = (size_t)NB * T_SEQ;          // 4096
  ushort_t* xb   = (ushort_t*)alloc(MT * DMODEL * 2);
  ushort_t* wab  = (ushort_t*)alloc((size_t)3 * DMODEL * DMODEL * 2);
  ushort_t* wpb  = (ushort_t*)alloc((size_t)DMODEL * DMODEL * 2);
  ushort_t* q_t  = (ushort_t*)alloc(MT * DMODEL * 2);
  ushort_t* k_t  = (ushort_t*)alloc(MT * DMODEL * 2);
  ushort_t* vtb  = (ushort_t*)alloc(MT * DMODEL * 2);
  ushort_t* yb   = (ushort_t*)alloc(MT * DMODEL * 2);
  float*    trig = (float*)alloc((size_t)T_SEQ * 64 * 2 * 4);
  (void)ws_size; (void)n_in; (void)in_sizes; (void)out_size;

  {  // converts
    int n8x = (int)(MT * DMODEL / 8);
    hipLaunchKernelGGL(cvt_f32_bf16, dim3((n8x + 255) / 256), dim3(256), 0, stream, x, xb, n8x);
    int n8a = (int)((size_t)3 * DMODEL * DMODEL / 8);
    hipLaunchKernelGGL(cvt_f32_bf16, dim3((n8a + 255) / 256), dim3(256), 0, stream, w_attn, wab, n8a);
    int n8p = (int)((size_t)DMODEL * DMODEL / 8);
    hipLaunchKernelGGL(cvt_f32_bf16, dim3((n8p + 255) / 256), dim3(256), 0, stream, w_proj, wpb, n8p);
  }
  hipLaunchKernelGGL(trig_init, dim3(T_SEQ * 64 / 256), dim3(256), 0, stream, trig);

  // QKV projection with fused RoPE (q,k) and fused V-transpose
  hipLaunchKernelGGL((gemm_bt<1>), dim3(3 * DMODEL / 128, MT / 128), dim3(256), 0, stream,
                     xb, wab, (float*)nullptr, q_t, k_t, vtb, trig,
                     (int)MT, 3 * DMODEL, DMODEL);

  hipLaunchKernelGGL(flash_attn, dim3(T_SEQ / 128, NB * NH), dim3(256), 0, stream,
                     q_t, k_t, vtb, yb);

  hipLaunchKernelGGL((gemm_bt<0>), dim3(DMODEL / 128, MT / 128), dim3(256), 0, stream,
                     yb, wpb, out, (ushort_t*)nullptr, (ushort_t*)nullptr, (ushort_t*)nullptr,
                     (const float*)nullptr, (int)MT, DMODEL, DMODEL);
}

// Round 5
// 300.400 us; speedup vs baseline: 1.3887x; 1.0581x over previous
//
#include <hip/hip_runtime.h>
#include <hip/hip_bf16.h>

#define T_SEQ 2048
#define DMODEL 2048
#define NB 2
#define NH 16
#define HD 128
#define BK 64

typedef __attribute__((ext_vector_type(8))) short short8;
typedef __attribute__((ext_vector_type(4))) float f32x4;
typedef __attribute__((ext_vector_type(16))) float f32x16;
typedef unsigned short ushort_t;

__device__ inline ushort_t f2bf(float f) {
  union { float f; unsigned u; } v; v.f = f;
  unsigned r = v.u + 0x7fffu + ((v.u >> 16) & 1u);
  return (ushort_t)(r >> 16);
}
__device__ inline float bf2f(ushort_t u) {
  union { unsigned u; float f; } v; v.u = ((unsigned)u) << 16;
  return v.f;
}
__device__ inline unsigned pk2(float x, float y) {
  union { __hip_bfloat162 h; unsigned u; } c;
  c.h = __float22bfloat162_rn(float2{x, y});
  return c.u;
}
__device__ inline float fexp2(float x) {
  float r;
  asm("v_exp_f32 %0, %1" : "=v"(r) : "v"(x));
  return r;
}

__device__ inline void gload16(const void* g, void* l) {
  __builtin_amdgcn_global_load_lds(
      (const __attribute__((address_space(1))) unsigned*)g,
      (__attribute__((address_space(3))) unsigned*)l, 16, 0, 0);
}

// ---------------- fp32 -> bf16 convert, 8 elems/thread ----------------
__global__ void cvt_f32_bf16(const float* __restrict__ src, ushort_t* __restrict__ dst, int n8) {
  int i = blockIdx.x * blockDim.x + threadIdx.x;
  if (i >= n8) return;
  const float4* s = (const float4*)src + (size_t)i * 2;
  float4 a = s[0], b = s[1];
  short8 o;
  o[0] = (short)f2bf(a.x); o[1] = (short)f2bf(a.y);
  o[2] = (short)f2bf(a.z); o[3] = (short)f2bf(a.w);
  o[4] = (short)f2bf(b.x); o[5] = (short)f2bf(b.y);
  o[6] = (short)f2bf(b.z); o[7] = (short)f2bf(b.w);
  *((short8*)dst + i) = o;
}

// ---------------- cos/sin table: trig[t*128 + i*2]=cos, +1=sin --------
__global__ void trig_init(float* __restrict__ trig) {
  int idx = blockIdx.x * blockDim.x + threadIdx.x;  // T*64
  if (idx >= T_SEQ * 64) return;
  int i = idx & 63, t = idx >> 6;
  float inv = __expf(-(float)i * (9.210340371976184f / 64.0f));
  float f = (float)t * inv;
  trig[idx * 2]     = cosf(f);
  trig[idx * 2 + 1] = sinf(f);
}

// ---------------- V transpose: [B][H][T][128] -> [B][H][128][T] -------
__global__ __launch_bounds__(256)
void v_transpose(const ushort_t* __restrict__ v, ushort_t* __restrict__ vt) {
  __shared__ __align__(16) ushort_t L[64][136];
  int bh = blockIdx.y;
  int t0 = blockIdx.x * 64;
  int tid = threadIdx.x;
  int row = tid >> 2, c0 = (tid & 3) * 32;
  const ushort_t* src = v + ((size_t)bh * T_SEQ + t0 + row) * HD + c0;
#pragma unroll
  for (int j = 0; j < 4; ++j)
    *(short8*)&L[row][c0 + j * 8] = *(const short8*)(src + j * 8);
  __syncthreads();
  int d = tid >> 1, tc = (tid & 1) * 32;
  union { ushort_t u[32]; short8 v8[4]; } buf;
#pragma unroll
  for (int j = 0; j < 32; ++j) buf.u[j] = L[tc + j][d];
  ushort_t* dst = vt + ((size_t)bh * HD + d) * T_SEQ + t0 + tc;
#pragma unroll
  for (int j = 0; j < 4; ++j) *(short8*)(dst + j * 8) = buf.v8[j];
}

// ============== 256x256 4-phase pipelined GEMM (bf16, fp32 acc) =======
// C = A[M][K] * Bt[N][K]^T. 512 thr = 8 waves (2M x 4N), per-wave 128x64.
// LDS: A,B tiles [256][64] double-buffered = 128 KiB, chunk^=(row&7) swizzle.
// Per K-tile: 4 phases {ds_read quadrant | prefetch next half-tiles |
// barrier | lgkmcnt0 | 16 MFMA (setprio) | barrier}; vmcnt(0) only at
// phase 3 (loads issued phases 0-1 get ~3 phases to land).
// EPI=0: C fp32 [M][N].  EPI=1: q,k rope-fused scatter; v plain scatter.
template <int EPI>
__global__ __launch_bounds__(512, 2)
void gemm256(const ushort_t* __restrict__ A, const ushort_t* __restrict__ Bt,
             float* __restrict__ C, ushort_t* __restrict__ q_t,
             ushort_t* __restrict__ k_t, ushort_t* __restrict__ v_t,
             const float* __restrict__ trig, int M, int N, int K) {
  __shared__ __align__(16) ushort_t sA[2][256 * 64];  // 64 KiB
  __shared__ __align__(16) ushort_t sB[2][256 * 64];  // 64 KiB
  int tid = threadIdx.x, lane = tid & 63, w = tid >> 6;
  int wm = w >> 2, wn = w & 3;
  int li = lane & 15, lg = lane >> 4;
  int tile_m = blockIdx.y * 256, tile_n = blockIdx.x * 256;
  const ushort_t* Ag = A + (size_t)tile_m * K;
  const ushort_t* Bg = Bt + (size_t)tile_n * K;

  // staging: inst (w,i) fills LDS bytes [w*2048 + i*1024, +1024) of a half.
  // lane covers row = base + (lane>>3), linear chunk (lane&7); the linear
  // chunk holds logical k-chunk (lane&7)^(row&7) -> pre-swizzled source.
  int srow = w * 16 + (lane >> 3);
  int schunk = ((lane & 7) ^ (lane >> 3)) * 8;

  auto stageA = [&](int half, int kt, int buf) {
#pragma unroll
    for (int i = 0; i < 2; ++i) {
      int row = half * 128 + srow + i * 8;
      gload16(Ag + (size_t)row * K + kt * BK + schunk,
              &sA[buf][half * 8192 + w * 1024 + i * 512]);
    }
  };
  auto stageB = [&](int half, int kt, int buf) {
#pragma unroll
    for (int i = 0; i < 2; ++i) {
      int row = half * 128 + srow + i * 8;
      gload16(Bg + (size_t)row * K + kt * BK + schunk,
              &sB[buf][half * 8192 + w * 1024 + i * 512]);
    }
  };

  f32x4 acc[8][4] = {};
  short8 bfr[4][2];
  const int NT = K / BK;

  stageA(0, 0, 0); stageA(1, 0, 0); stageB(0, 0, 0); stageB(1, 0, 0);
  asm volatile("s_waitcnt vmcnt(0)" ::: "memory");
  __syncthreads();

  for (int kt = 0; kt < NT; ++kt) {
    int cur = kt & 1;
    bool pref = (kt + 1 < NT);
#pragma unroll
    for (int p = 0; p < 4; ++p) {
      short8 af[2][2];
#pragma unroll
      for (int mm = 0; mm < 2; ++mm) {
        int row = wm * 128 + (p * 2 + mm) * 16 + li;
#pragma unroll
        for (int kh = 0; kh < 2; ++kh)
          af[mm][kh] = *(const short8*)&sA[cur][row * 64 + (((kh * 4 + lg) ^ (row & 7)) * 8)];
      }
      if (p == 0) {
#pragma unroll
        for (int n = 0; n < 4; ++n) {
          int row = wn * 64 + n * 16 + li;
#pragma unroll
          for (int kh = 0; kh < 2; ++kh)
            bfr[n][kh] = *(const short8*)&sB[cur][row * 64 + (((kh * 4 + lg) ^ (row & 7)) * 8)];
        }
      }
      if (pref) {
        if (p == 0) { stageA(0, kt + 1, cur ^ 1); stageB(0, kt + 1, cur ^ 1); }
        else if (p == 1) { stageA(1, kt + 1, cur ^ 1); stageB(1, kt + 1, cur ^ 1); }
      }
      __builtin_amdgcn_s_barrier();
      asm volatile("s_waitcnt lgkmcnt(0)" ::: "memory");
      __builtin_amdgcn_sched_barrier(0);
      __builtin_amdgcn_s_setprio(1);
#pragma unroll
      for (int mm = 0; mm < 2; ++mm)
#pragma unroll
        for (int n = 0; n < 4; ++n)
#pragma unroll
          for (int kh = 0; kh < 2; ++kh)
            acc[p * 2 + mm][n] = __builtin_amdgcn_mfma_f32_16x16x32_bf16(
                af[mm][kh], bfr[n][kh], acc[p * 2 + mm][n], 0, 0, 0);
      __builtin_amdgcn_s_setprio(0);
      if (p == 3) asm volatile("s_waitcnt vmcnt(0)" ::: "memory");
      __builtin_amdgcn_s_barrier();
    }
  }

  if (EPI == 0) {
#pragma unroll
    for (int m = 0; m < 8; ++m) {
      int trow = tile_m + wm * 128 + m * 16 + lg * 4;
#pragma unroll
      for (int n = 0; n < 4; ++n) {
        int col = tile_n + wn * 64 + n * 16 + li;
#pragma unroll
        for (int r = 0; r < 4; ++r)
          C[(size_t)(trow + r) * N + col] = acc[m][n][r];
      }
    }
  } else {
    int sec = tile_n >> 11;          // block-uniform (tile inside one section)
    int bq  = tile_m >> 11;
    int t0  = tile_m & 2047;
#pragma unroll
    for (int m = 0; m < 8; ++m) {
      int tl = wm * 128 + m * 16 + lg * 4;
#pragma unroll
      for (int n = 0; n < 4; ++n) {
        int nn = (tile_n & 2047) + wn * 64 + n * 16 + li;
        int h = nn >> 7, d = nn & 127;
        if (sec < 2) {
          ushort_t* base = ((sec == 0) ? q_t : k_t) + ((size_t)(bq * NH + h)) * T_SEQ * HD;
          int fi2 = (d >> 1) * 2;
#pragma unroll
          for (int r = 0; r < 4; ++r) {
            int t = t0 + tl + r;
            float val = acc[m][n][r];
            float par = __shfl_xor(val, 1);
            const float* tp = trig + t * 128 + fi2;
            float c = tp[0], s = tp[1];
            float outv = (li & 1) ? (par * s + val * c) : (val * c - par * s);
            base[(size_t)t * HD + d] = f2bf(outv);
          }
        } else {
          ushort_t* base = v_t + ((size_t)(bq * NH + h)) * T_SEQ * HD;
#pragma unroll
          for (int r = 0; r < 4; ++r)
            base[(size_t)(t0 + tl + r) * HD + d] = f2bf(acc[m][n][r]);
        }
      }
    }
  }
}

// ---------------- Flash attention (causal), swapped-QK 32x32 ----------
__global__ __launch_bounds__(256, 2)
void flash_attn(const ushort_t* __restrict__ Q, const ushort_t* __restrict__ Kg,
                const ushort_t* __restrict__ Vt, ushort_t* __restrict__ Y) {
  __shared__ __align__(16) ushort_t ldsK[2 * 64 * 128];   // 32KB, 2 buf
  __shared__ __align__(16) ushort_t ldsV[2 * 128 * 64];   // 32KB, 2 buf
  int tid = threadIdx.x, lane = tid & 63, w = tid >> 6;
  int hi = lane >> 5, l31 = lane & 31;
  int qi = (blockIdx.y & 16) ? (15 - (int)blockIdx.x) : (int)blockIdx.x;
  int bh = blockIdx.y;
  int b = bh >> 4, h = bh & 15;
  int q0 = qi * 128;
  const ushort_t* Qp = Q + (size_t)bh * T_SEQ * HD;
  const ushort_t* Kp = Kg + (size_t)bh * T_SEQ * HD;
  const ushort_t* Vp = Vt + (size_t)bh * HD * T_SEQ;

  int qg = q0 + w * 32 + l31;
  int qmaxw = q0 + w * 32 + 31;

  auto stage = [&](int kv0, int bsel) {
    ushort_t* Kb = ldsK + bsel * 8192;
    ushort_t* Vb = ldsV + bsel * 8192;
#pragma unroll
    for (int p = 0; p < 4; ++p) {
      int c = p * 256 + w * 64 + lane;
      {
        int row = c >> 4, cc = c & 15;
        int sc = cc ^ (row & 15);
        gload16(Kp + (size_t)(kv0 + row) * HD + sc * 8, Kb + (p * 256 + w * 64) * 8);
      }
      {
        int d = c >> 3, cc = c & 7;
        int sc = cc ^ (d & 7);
        gload16(Vp + (size_t)d * T_SEQ + kv0 + sc * 8, Vb + (p * 256 + w * 64) * 8);
      }
    }
  };

  short8 qf[8];
#pragma unroll
  for (int ds = 0; ds < 8; ++ds)
    qf[ds] = *(const short8*)(Qp + (size_t)qg * HD + ds * 16 + hi * 8);

  f32x16 o[4] = {};
  float mu = -1e30f, l = 0.f;
  const float SIG = 0.12751879523209784f;  // (1/sqrt(128)) * log2(e)

  int nkt = 2 * qi + 2;
  stage(0, 0);
  __syncthreads();
  int cur = 0;
  for (int kt = 0; kt < nkt; ++kt) {
    int kv0 = kt * 64;
    if (kt + 1 < nkt) stage((kt + 1) * 64, cur ^ 1);
    if (kv0 <= qmaxw) {
      const ushort_t* Kb = ldsK + cur * 8192;
      const ushort_t* Vb = ldsV + cur * 8192;
      f32x16 sa = {}, sb = {};
      __builtin_amdgcn_s_setprio(1);
#pragma unroll
      for (int ds = 0; ds < 8; ++ds) {
        int cc = ds * 2 + hi;
        short8 k0 = *(const short8*)&Kb[l31 * 128 + ((cc ^ (l31 & 15)) * 8)];
        short8 k1 = *(const short8*)&Kb[(32 + l31) * 128 + ((cc ^ (l31 & 15)) * 8)];
        sa = __builtin_amdgcn_mfma_f32_32x32x16_bf16(k0, qf[ds], sa, 0, 0, 0);
        sb = __builtin_amdgcn_mfma_f32_32x32x16_bf16(k1, qf[ds], sb, 0, 0, 0);
      }
      __builtin_amdgcn_s_setprio(0);
      float p[32];
#pragma unroll
      for (int r = 0; r < 16; ++r) { p[r] = sa[r] * SIG; p[16 + r] = sb[r] * SIG; }
      if (kv0 + 63 > q0 + w * 32) {
#pragma unroll
        for (int r = 0; r < 16; ++r) {
          int loc = (r & 3) + 8 * (r >> 2) + 4 * hi;
          if (kv0 + loc > qg)      p[r]      = -3e38f;
          if (kv0 + 32 + loc > qg) p[16 + r] = -3e38f;
        }
      }
      float tm[16];
#pragma unroll
      for (int i = 0; i < 16; ++i) tm[i] = fmaxf(p[i], p[i + 16]);
#pragma unroll
      for (int st = 8; st >= 1; st >>= 1)
#pragma unroll
        for (int i = 0; i < 8; ++i)
          if (i < st) tm[i] = fmaxf(tm[i], tm[i + st]);
      float pmax = fmaxf(tm[0], __shfl_xor(tm[0], 32));
      bool resc = !__all(pmax <= mu + 11.0f);
      if (resc) {
        float munew = fmaxf(mu, pmax);
        float alpha = fexp2(mu - munew);
        mu = munew;
        l *= alpha;
#pragma unroll
        for (int dsub = 0; dsub < 4; ++dsub)
#pragma unroll
          for (int r = 0; r < 16; ++r) o[dsub][r] *= alpha;
      }
#pragma unroll
      for (int i = 0; i < 32; ++i) p[i] = fexp2(p[i] - mu);
      float ts[16];
#pragma unroll
      for (int i = 0; i < 16; ++i) ts[i] = p[i] + p[i + 16];
#pragma unroll
      for (int st = 8; st >= 1; st >>= 1)
#pragma unroll
        for (int i = 0; i < 8; ++i)
          if (i < st) ts[i] += ts[i + st];
      l += ts[0] + __shfl_xor(ts[0], 32);
      __builtin_amdgcn_s_setprio(1);
#pragma unroll
      for (int s = 0; s < 4; ++s) {
        int rb = (s >> 1) * 16 + (s & 1) * 8;
        unsigned a0 = pk2(p[rb + 0], p[rb + 1]);
        unsigned a1 = pk2(p[rb + 2], p[rb + 3]);
        unsigned a2 = pk2(p[rb + 4], p[rb + 5]);
        unsigned a3 = pk2(p[rb + 6], p[rb + 7]);
        unsigned sa0 = (unsigned)__shfl_xor((int)a0, 32);
        unsigned sa1 = (unsigned)__shfl_xor((int)a1, 32);
        unsigned sa2 = (unsigned)__shfl_xor((int)a2, 32);
        unsigned sa3 = (unsigned)__shfl_xor((int)a3, 32);
        union { unsigned u[4]; short8 s8; } pf;
        pf.u[0] = hi ? sa2 : a0;
        pf.u[1] = hi ? sa3 : a1;
        pf.u[2] = hi ? a2 : sa0;
        pf.u[3] = hi ? a3 : sa1;
#pragma unroll
        for (int dsub = 0; dsub < 4; ++dsub) {
          int row = dsub * 32 + l31;
          short8 vf = *(const short8*)&Vb[row * 64 + (((2 * s + hi) ^ (row & 7)) * 8)];
          o[dsub] = __builtin_amdgcn_mfma_f32_32x32x16_bf16(vf, pf.s8, o[dsub], 0, 0, 0);
        }
      }
      __builtin_amdgcn_s_setprio(0);
    }
    __syncthreads();
    cur ^= 1;
  }
  float invl = 1.f / l;
#pragma unroll
  for (int dsub = 0; dsub < 4; ++dsub)
#pragma unroll
    for (int r = 0; r < 16; ++r) o[dsub][r] *= invl;
#pragma unroll
  for (int dsub = 0; dsub < 4; ++dsub)
#pragma unroll
    for (int r = 0; r < 16; r += 2) {
      int d0 = dsub * 32 + (r & 3) + 8 * (r >> 2) + 4 * hi;
      unsigned u = pk2(o[dsub][r], o[dsub][r + 1]);
      *(unsigned*)&ldsK[w * 4096 + l31 * 128 + (((d0 >> 3) ^ (l31 & 15)) * 8) + (d0 & 7)] = u;
    }
  __syncthreads();
#pragma unroll
  for (int rep = 0; rep < 8; ++rep) {
    int idx = rep * 256 + tid;
    int qg2 = idx >> 4, c = idx & 15;
    int wv2 = qg2 >> 5, ql = qg2 & 31;
    short8 val = *(const short8*)&ldsK[wv2 * 4096 + ql * 128 + ((c ^ (ql & 15)) * 8)];
    *(short8*)(Y + ((size_t)(b * T_SEQ + q0 + qg2)) * DMODEL + h * HD + c * 8) = val;
  }
}

extern "C" void kernel_launch(void* const* d_in, const int* in_sizes, int n_in,
                              void* d_out, int out_size, void* d_ws, size_t ws_size,
                              hipStream_t stream) {
  const float* x      = (const float*)d_in[0];
  const float* w_attn = (const float*)d_in[1];
  const float* w_proj = (const float*)d_in[2];
  float* out = (float*)d_out;

  char* ws = (char*)d_ws;
  size_t off = 0;
  auto alloc = [&](size_t bytes) -> void* {
    void* p = ws + off;
    off = (off + bytes + 255) & ~(size_t)255;
    return p;
  };
  const size_t MT = (size_t)NB * T_SEQ;          // 4096
  ushort_t* xb   = (ushort_t*)alloc(MT * DMODEL * 2);
  ushort_t* wab  = (ushort_t*)alloc((size_t)3 * DMODEL * DMODEL * 2);
  ushort_t* wpb  = (ushort_t*)alloc((size_t)DMODEL * DMODEL * 2);
  ushort_t* q_t  = (ushort_t*)alloc(MT * DMODEL * 2);
  ushort_t* k_t  = (ushort_t*)alloc(MT * DMODEL * 2);
  ushort_t* v_t  = (ushort_t*)alloc(MT * DMODEL * 2);
  ushort_t* vtb  = (ushort_t*)alloc(MT * DMODEL * 2);
  ushort_t* yb   = (ushort_t*)alloc(MT * DMODEL * 2);
  float*    trig = (float*)alloc((size_t)T_SEQ * 64 * 2 * 4);
  (void)ws_size; (void)n_in; (void)in_sizes; (void)out_size;

  {  // converts
    int n8x = (int)(MT * DMODEL / 8);
    hipLaunchKernelGGL(cvt_f32_bf16, dim3((n8x + 255) / 256), dim3(256), 0, stream, x, xb, n8x);
    int n8a = (int)((size_t)3 * DMODEL * DMODEL / 8);
    hipLaunchKernelGGL(cvt_f32_bf16, dim3((n8a + 255) / 256), dim3(256), 0, stream, w_attn, wab, n8a);
    int n8p = (int)((size_t)DMODEL * DMODEL / 8);
    hipLaunchKernelGGL(cvt_f32_bf16, dim3((n8p + 255) / 256), dim3(256), 0, stream, w_proj, wpb, n8p);
  }
  hipLaunchKernelGGL(trig_init, dim3(T_SEQ * 64 / 256), dim3(256), 0, stream, trig);

  // QKV projection (256^2 4-phase), rope fused for q/k, plain v scatter
  hipLaunchKernelGGL((gemm256<1>), dim3(3 * DMODEL / 256, MT / 256), dim3(512), 0, stream,
                     xb, wab, (float*)nullptr, q_t, k_t, v_t, trig,
                     (int)MT, 3 * DMODEL, DMODEL);

  hipLaunchKernelGGL(v_transpose, dim3(T_SEQ / 64, NB * NH), dim3(256), 0, stream, v_t, vtb);

  hipLaunchKernelGGL(flash_attn, dim3(T_SEQ / 128, NB * NH), dim3(256), 0, stream,
                     q_t, k_t, vtb, yb);

  // output projection (256^2 4-phase)
  hipLaunchKernelGGL((gemm256<0>), dim3(DMODEL / 256, MT / 256), dim3(512), 0, stream,
                     yb, wpb, out, (ushort_t*)nullptr, (ushort_t*)nullptr, (ushort_t*)nullptr,
                     (const float*)nullptr, (int)MT, DMODEL, DMODEL);
}